// Round 7
// baseline (787.058 us; speedup 1.0000x reference)
//
#include <hip/hip_runtime.h>
#include <math.h>

#define NEG_SLOPE 0.2f

typedef unsigned short u16;
typedef unsigned int u32;
typedef __attribute__((ext_vector_type(8))) short bf16x8;
typedef __attribute__((ext_vector_type(8))) _Float16 f16x8;
typedef __attribute__((ext_vector_type(4))) float f32x4;

__device__ __forceinline__ float wave_sum(float v){
  #pragma unroll
  for (int o = 1; o < 64; o <<= 1) v += __shfl_xor(v, o, 64);
  return v;
}

__device__ __forceinline__ u16 f2bf(float f){
  u32 u = __float_as_uint(f);
  return (u16)((u + 0x7FFF + ((u >> 16) & 1)) >> 16);
}
__device__ __forceinline__ float bf2f(u16 h){
  return __uint_as_float(((u32)h) << 16);
}

__device__ __forceinline__ void gl_lds16(const void* g, void* l){
  __builtin_amdgcn_global_load_lds((const __attribute__((address_space(1))) u32*)g,
                                   (__attribute__((address_space(3))) u32*)l, 16, 0, 0);
}

// ---------------- edge-weight mean (sum; divide later) ----------------
__global__ void k_sum_ew(const float* __restrict__ ew, int E, float* __restrict__ out){
  float s = 0.f;
  for (int i = blockIdx.x*blockDim.x + threadIdx.x; i < E; i += gridDim.x*blockDim.x) s += ew[i];
  s = wave_sum(s);
  __shared__ float red[4];
  int lane = threadIdx.x & 63, wid = threadIdx.x >> 6;
  if (lane == 0) red[wid] = s;
  __syncthreads();
  if (threadIdx.x == 0){
    float t = 0.f;
    for (int i = 0; i < (int)(blockDim.x >> 6); i++) t += red[i];
    atomicAdd(out, t);
  }
}

// ---------------- degree histogram (dst) ----------------
__global__ void k_deg(const int* __restrict__ dst, int E, int* __restrict__ deg){
  int i = blockIdx.x*blockDim.x + threadIdx.x;
  if (i < E) atomicAdd(&deg[dst[i]], 1);
}

// ---------------- exclusive scan over N nodes (deg+1 each: self loops) ----------------
__global__ __launch_bounds__(1024) void k_scan(const int* __restrict__ deg, int* __restrict__ rowptr,
                                               int* __restrict__ cursor, int n){
  __shared__ int sums[1024];
  int t = threadIdx.x;
  int CH = (n + 1023) >> 10;
  int base = t*CH;
  int local = 0;
  for (int i = 0; i < CH; i++){ int idx = base + i; if (idx < n) local += deg[idx] + 1; }
  sums[t] = local;
  __syncthreads();
  for (int off = 1; off < 1024; off <<= 1){
    int v = (t >= off) ? sums[t-off] : 0;
    __syncthreads();
    sums[t] += v;
    __syncthreads();
  }
  int run = sums[t] - local;   // exclusive prefix
  for (int i = 0; i < CH; i++){
    int idx = base + i;
    if (idx < n){ rowptr[idx] = run; cursor[idx] = run; run += deg[idx] + 1; }
  }
  if (t == 0) rowptr[n] = sums[1023];
}

// ---------------- scatter edges (+ self loops) into CSR ----------------
__global__ void k_scatter(const int* __restrict__ ei, const float* __restrict__ ew, int E, int n,
                          const float* __restrict__ sum_ew, int* __restrict__ cursor,
                          int* __restrict__ csr_src, float* __restrict__ csr_w){
  int i = blockIdx.x*blockDim.x + threadIdx.x;
  if (i >= E + n) return;
  if (i < E){
    int s = ei[i];         // row 0 = src
    int d = ei[E + i];     // row 1 = dst
    int pos = atomicAdd(&cursor[d], 1);
    csr_src[pos] = s; csr_w[pos] = ew[i];
  } else {
    int v = i - E;
    int pos = atomicAdd(&cursor[v], 1);
    csr_src[pos] = v; csr_w[pos] = (*sum_ew) / (float)E;
  }
}

// ---------------- split f32 -> bf16 hi/lo planes ----------------
__global__ void k_split(const float* __restrict__ in, u16* __restrict__ hi, u16* __restrict__ lo, int m){
  for (int i = blockIdx.x*blockDim.x + threadIdx.x; i < m; i += gridDim.x*blockDim.x){
    float a = in[i];
    u16 h = f2bf(a);
    hi[i] = h;
    lo[i] = f2bf(a - bf2f(h));
  }
}

// ---------------- layer-1 linear: x(Nx16) -> xl,xr (Nx512) f16 ----------------
__global__ __launch_bounds__(256) void k_lin1(const float* __restrict__ x,
        const float* __restrict__ Wl, const float* __restrict__ bl,
        const float* __restrict__ Wr, const float* __restrict__ br,
        _Float16* __restrict__ xl, _Float16* __restrict__ xr, int n){
  __shared__ float Ws[16][1028];   // transposed, padded
  __shared__ float bs[1024];
  __shared__ float xs[32][16];
  int t = threadIdx.x;
  for (int i = t; i < 512*16; i += 256){
    int j = i >> 4, k = i & 15;
    Ws[k][j] = Wl[i];
    Ws[k][512 + j] = Wr[i];
  }
  for (int i = t; i < 512; i += 256){ bs[i] = bl[i]; bs[512 + i] = br[i]; }
  int n0 = blockIdx.x * 32;
  for (int i = t; i < 32*16; i += 256){ int r = i >> 4, k = i & 15; xs[r][k] = x[(size_t)(n0 + r)*16 + k]; }
  __syncthreads();
  for (int idx = t; idx < 32*1024; idx += 256){
    int r = idx >> 10, c = idx & 1023;
    float s = bs[c];
    #pragma unroll
    for (int k = 0; k < 16; k++) s += xs[r][k] * Ws[k][c];
    int nn = n0 + r;
    if (c < 512) xl[(size_t)nn*512 + c] = (_Float16)s;
    else         xr[(size_t)nn*512 + (c - 512)] = (_Float16)s;
  }
}

// ---------------- split-bf16 MFMA GEMM, f16 output ----------------
__global__ __launch_bounds__(256,2) void k_gemm_mfma(
    const u16* __restrict__ Ah, const u16* __restrict__ Al,
    const u16* __restrict__ Wh, const u16* __restrict__ Wl,
    const float* __restrict__ bias, _Float16* __restrict__ out,
    int n, int K, int J){
  __shared__ __align__(16) u16 lds[16384];   // 32KB: Ah,Al,Wh,Wl planes of 4096 u16
  u16* lA_h = lds;
  u16* lA_l = lds + 4096;
  u16* lW_h = lds + 8192;
  u16* lW_l = lds + 12288;
  int t = threadIdx.x;
  int lane = t & 63, w = t >> 6;
  int lane15 = lane & 15, lgrp = lane >> 4;
  int n0 = blockIdx.y * 128, j0 = blockIdx.x * 128;
  int wm = (w >> 1) * 64, wn = (w & 1) * 64;
  f32x4 acc[4][4] = {};

  int s0 = t, s1 = t + 256;
  int r0 = s0 >> 2, r1 = s1 >> 2;
  int sl0 = (s0 & 3) ^ ((r0 >> 1) & 3);
  int sl1 = (s1 & 3) ^ ((r1 >> 1) & 3);
  size_t arow0 = (size_t)min(n0 + r0, n - 1) * K + sl0*8;
  size_t arow1 = (size_t)min(n0 + r1, n - 1) * K + sl1*8;
  size_t wrow0 = (size_t)(j0 + r0) * K + sl0*8;
  size_t wrow1 = (size_t)(j0 + r1) * K + sl1*8;

  int rcol = (lgrp * 16) ^ (((lane15 >> 1) & 3) << 4);

  for (int k0 = 0; k0 < K; k0 += 32){
    gl_lds16(Ah + arow0 + k0, lA_h + s0*8);
    gl_lds16(Ah + arow1 + k0, lA_h + s1*8);
    gl_lds16(Al + arow0 + k0, lA_l + s0*8);
    gl_lds16(Al + arow1 + k0, lA_l + s1*8);
    gl_lds16(Wh + wrow0 + k0, lW_h + s0*8);
    gl_lds16(Wh + wrow1 + k0, lW_h + s1*8);
    gl_lds16(Wl + wrow0 + k0, lW_l + s0*8);
    gl_lds16(Wl + wrow1 + k0, lW_l + s1*8);
    __syncthreads();
    bf16x8 ah[4], al[4], bh[4], bl_[4];
    #pragma unroll
    for (int i = 0; i < 4; i++){
      int qa = (wm + i*16 + lane15)*64 + rcol;
      ah[i]  = *(const bf16x8*)((const char*)lA_h + qa);
      al[i]  = *(const bf16x8*)((const char*)lA_l + qa);
      int qb = (wn + i*16 + lane15)*64 + rcol;
      bh[i]  = *(const bf16x8*)((const char*)lW_h + qb);
      bl_[i] = *(const bf16x8*)((const char*)lW_l + qb);
    }
    #pragma unroll
    for (int mi = 0; mi < 4; mi++)
      #pragma unroll
      for (int ni = 0; ni < 4; ni++){
        acc[mi][ni] = __builtin_amdgcn_mfma_f32_16x16x32_bf16(ah[mi], bh[ni],  acc[mi][ni], 0, 0, 0);
        acc[mi][ni] = __builtin_amdgcn_mfma_f32_16x16x32_bf16(ah[mi], bl_[ni], acc[mi][ni], 0, 0, 0);
        acc[mi][ni] = __builtin_amdgcn_mfma_f32_16x16x32_bf16(al[mi], bh[ni],  acc[mi][ni], 0, 0, 0);
      }
    __syncthreads();
  }

  #pragma unroll
  for (int ni = 0; ni < 4; ni++){
    int col = j0 + wn + ni*16 + lane15;
    float bia = bias[col];
    #pragma unroll
    for (int mi = 0; mi < 4; mi++){
      int rowb = n0 + wm + mi*16 + lgrp*4;
      #pragma unroll
      for (int rg = 0; rg < 4; rg++){
        int row = rowb + rg;
        if (row < n) out[(size_t)row*J + col] = (_Float16)(acc[mi][ni][rg] + bia);
      }
    }
  }
}

// ---------------- GATv2 edge-softmax + aggregation + bias + LayerNorm (+ELU) ----------------
// HEADS==4: one node per block (4 waves = 4 heads). HEADS==1: 4 nodes per block,
// one per wave. Within a wave: 4 groups x 16 lanes; each group batches FOUR edges
// per iteration (4 independent 16B gathers in flight -> latency-chain collapse).
// Defer-max online softmax (THR=8) applied once per quad.
template<int HEADS, bool DO_ELU, bool EMIT>
__global__ __launch_bounds__(256) void k_agg(
                      const _Float16* __restrict__ xl, const _Float16* __restrict__ xr,
                      const float* __restrict__ We, const float* __restrict__ att, const float* __restrict__ bo,
                      const float* __restrict__ gam, const float* __restrict__ bet,
                      const int* __restrict__ rowptr, const int* __restrict__ csr_src,
                      const float* __restrict__ csr_w,
                      float* __restrict__ out, u16* __restrict__ oh, u16* __restrict__ ol, int n){
  constexpr int HC_ = HEADS * 128;
  constexpr float RT = 8.f;
  int t = threadIdx.x, lane = t & 63, w = t >> 6;
  int l16 = lane & 15, grp = lane >> 4;
  int h = (HEADS == 4) ? w : 0;
  int c0 = h*128 + l16*8;          // 8 channels per lane

  int nid = (HEADS == 4) ? blockIdx.x : blockIdx.x*4 + w;
  if (nid >= n) return;            // wave-uniform; HEADS==4 grid is exact

  // hoisted per-layer params
  float4 wea = *(const float4*)&We[c0],  web = *(const float4*)&We[c0 + 4];
  float4 ata = *(const float4*)&att[c0], atb = *(const float4*)&att[c0 + 4];
  float we8[8] = {wea.x,wea.y,wea.z,wea.w,web.x,web.y,web.z,web.w};
  float at8[8] = {ata.x,ata.y,ata.z,ata.w,atb.x,atb.y,atb.z,atb.w};

  f16x8 xrh = *(const f16x8*)(xr + (size_t)nid*HC_ + c0);
  float xr8[8];
  #pragma unroll
  for (int j = 0; j < 8; j++) xr8[j] = (float)xrh[j];

  int rs = rowptr[nid], re = rowptr[nid + 1];
  float m = -3e38f, d = 0.f;
  float acc[8] = {};
  for (int base = rs + grp; base < re; base += 16){
    // 4 batched edges per group: base, base+4, base+8, base+12
    int   eidx[4]; bool has[4]; int src[4]; float ww[4];
    #pragma unroll
    for (int u = 0; u < 4; u++){
      int ee = base + 4*u;
      has[u]  = ee < re;
      eidx[u] = has[u] ? ee : rs;      // clamp to a safe slot
    }
    #pragma unroll
    for (int u = 0; u < 4; u++){ src[u] = csr_src[eidx[u]]; }
    #pragma unroll
    for (int u = 0; u < 4; u++){ float wv = csr_w[eidx[u]]; ww[u] = has[u] ? wv : 0.f; }
    // 4 independent gathers in flight
    f16x8 hv[4];
    #pragma unroll
    for (int u = 0; u < 4; u++) hv[u] = *(const f16x8*)(xl + (size_t)src[u]*HC_ + c0);
    float v[4][8];
    #pragma unroll
    for (int u = 0; u < 4; u++)
      #pragma unroll
      for (int j = 0; j < 8; j++) v[u][j] = (float)hv[u][j];
    float p[4] = {0.f, 0.f, 0.f, 0.f};
    #pragma unroll
    for (int u = 0; u < 4; u++)
      #pragma unroll
      for (int j = 0; j < 8; j++){
        float tv = v[u][j] + xr8[j] + ww[u]*we8[j];
        tv = (tv > 0.f) ? tv : NEG_SLOPE*tv;
        p[u] += tv * at8[j];
      }
    #pragma unroll
    for (int o = 1; o < 16; o <<= 1){
      #pragma unroll
      for (int u = 0; u < 4; u++) p[u] += __shfl_xor(p[u], o, 64);
    }
    #pragma unroll
    for (int u = 0; u < 4; u++) if (!has[u]) p[u] = -3e38f;
    float pm = fmaxf(fmaxf(p[0], p[1]), fmaxf(p[2], p[3]));
    if (pm > m + RT){          // rare rescale (defer-max)
      float sc = __expf(m - pm);
      d *= sc;
      #pragma unroll
      for (int j = 0; j < 8; j++) acc[j] *= sc;
      m = pm;
    }
    float ex[4];
    #pragma unroll
    for (int u = 0; u < 4; u++) ex[u] = __expf(p[u] - m);
    d += (ex[0] + ex[1]) + (ex[2] + ex[3]);
    #pragma unroll
    for (int j = 0; j < 8; j++)
      acc[j] += (ex[0]*v[0][j] + ex[1]*v[1][j]) + (ex[2]*v[2][j] + ex[3]*v[3][j]);
  }
  // merge the 4 groups' online states (xor masks 16, 32)
  float M = m;
  M = fmaxf(M, __shfl_xor(M, 16, 64));
  M = fmaxf(M, __shfl_xor(M, 32, 64));
  float sc = __expf(m - M);
  float dd = d * sc;
  dd += __shfl_xor(dd, 16, 64);
  dd += __shfl_xor(dd, 32, 64);
  #pragma unroll
  for (int j = 0; j < 8; j++){
    float a = acc[j] * sc;
    a += __shfl_xor(a, 16, 64);
    a += __shfl_xor(a, 32, 64);
    acc[j] = a;
  }
  float inv = 1.f / (dd + 1e-16f);
  float o8[8];
  float4 boa = *(const float4*)&bo[c0], bob = *(const float4*)&bo[c0 + 4];
  float bo8[8] = {boa.x,boa.y,boa.z,boa.w,bob.x,bob.y,bob.z,bob.w};
  #pragma unroll
  for (int j = 0; j < 8; j++) o8[j] = acc[j]*inv + bo8[j];

  // LayerNorm over HC_ channels
  float s1 = 0.f, s2 = 0.f;
  #pragma unroll
  for (int j = 0; j < 8; j++){ s1 += o8[j]; s2 += o8[j]*o8[j]; }
  #pragma unroll
  for (int o = 1; o < 16; o <<= 1){ s1 += __shfl_xor(s1, o, 64); s2 += __shfl_xor(s2, o, 64); }
  float S1, S2;
  if (HEADS == 4){
    __shared__ float red[4][2];
    if (lane == 0){ red[w][0] = s1; red[w][1] = s2; }
    __syncthreads();
    S1 = red[0][0] + red[1][0] + red[2][0] + red[3][0];
    S2 = red[0][1] + red[1][1] + red[2][1] + red[3][1];
  } else {
    S1 = s1; S2 = s2;
  }
  float mu = S1 / (float)HC_;
  float var = S2 / (float)HC_ - mu*mu;
  float rstd = rsqrtf(var + 1e-5f);
  float4 ga = *(const float4*)&gam[c0], gb = *(const float4*)&gam[c0 + 4];
  float4 ba = *(const float4*)&bet[c0], bb = *(const float4*)&bet[c0 + 4];
  float g8[8] = {ga.x,ga.y,ga.z,ga.w,gb.x,gb.y,gb.z,gb.w};
  float b8[8] = {ba.x,ba.y,ba.z,ba.w,bb.x,bb.y,bb.z,bb.w};
  float y[8];
  #pragma unroll
  for (int j = 0; j < 8; j++){
    float yy = (o8[j] - mu)*rstd*g8[j] + b8[j];
    if (DO_ELU) yy = (yy > 0.f) ? yy : expm1f(yy);
    y[j] = yy;
  }
  if (grp == 0){
    if (EMIT){
      u32 hv2[4], lv2[4];
      #pragma unroll
      for (int j = 0; j < 4; j++){
        u16 h0 = f2bf(y[2*j]), h1 = f2bf(y[2*j+1]);
        u16 l0 = f2bf(y[2*j] - bf2f(h0)), l1 = f2bf(y[2*j+1] - bf2f(h1));
        hv2[j] = (u32)h0 | ((u32)h1 << 16);
        lv2[j] = (u32)l0 | ((u32)l1 << 16);
      }
      *(uint4*)&oh[(size_t)nid*HC_ + c0] = make_uint4(hv2[0],hv2[1],hv2[2],hv2[3]);
      *(uint4*)&ol[(size_t)nid*HC_ + c0] = make_uint4(lv2[0],lv2[1],lv2[2],lv2[3]);
    } else {
      float* orow = out + (size_t)nid*HC_ + c0;
      *(float4*)orow       = make_float4(y[0],y[1],y[2],y[3]);
      *(float4*)(orow + 4) = make_float4(y[4],y[5],y[6],y[7]);
    }
  }
}

// ---------------- policy/value heads on one node ----------------
__global__ __launch_bounds__(128) void k_heads(const float* __restrict__ h3, const int* __restrict__ idxp,
        const float* __restrict__ Pw1, const float* __restrict__ Pb1,
        const float* __restrict__ Pw2, const float* __restrict__ Pb2,
        const float* __restrict__ Vw1, const float* __restrict__ Vb1,
        const float* __restrict__ Vw2, const float* __restrict__ Vb2,
        float* __restrict__ out){
  __shared__ float z[128], hp[128], hv[128];
  int t = threadIdx.x;
  int idx = *idxp;
  z[t] = h3[(size_t)idx*128 + t];
  __syncthreads();
  float sp = Pb1[t], sv = Vb1[t];
  for (int c = 0; c < 128; c++){
    float zc = z[c];
    sp += Pw1[t*128 + c] * zc;
    sv += Vw1[t*128 + c] * zc;
  }
  hp[t] = fmaxf(sp, 0.f);
  hv[t] = fmaxf(sv, 0.f);
  __syncthreads();
  if (t < 64){
    float l0 = Pw2[t]*hp[t]       + Pw2[64 + t]*hp[64 + t];
    float l1 = Pw2[128 + t]*hp[t] + Pw2[192 + t]*hp[64 + t];
    float vv = Vw2[t]*hv[t]       + Vw2[64 + t]*hv[64 + t];
    #pragma unroll
    for (int o = 1; o < 64; o <<= 1){
      l0 += __shfl_xor(l0, o, 64); l1 += __shfl_xor(l1, o, 64); vv += __shfl_xor(vv, o, 64);
    }
    if (t == 0){ out[0] = l0 + Pb2[0]; out[1] = l1 + Pb2[1]; out[2] = vv + Vb2[0]; }
  }
}

extern "C" void kernel_launch(void* const* d_in, const int* in_sizes, int n_in,
                              void* d_out, int out_size, void* d_ws, size_t ws_size,
                              hipStream_t stream){
  const float* x    = (const float*)d_in[0];
  const int*   ei   = (const int*)d_in[1];
  const float* ew   = (const float*)d_in[2];
  const int*   nidx = (const int*)d_in[3];
  const float* Wl1 = (const float*)d_in[4];  const float* bl1 = (const float*)d_in[5];
  const float* Wr1 = (const float*)d_in[6];  const float* br1 = (const float*)d_in[7];
  const float* We1 = (const float*)d_in[8];  const float* att1 = (const float*)d_in[9];
  const float* bo1 = (const float*)d_in[10];
  const float* Wl2 = (const float*)d_in[11]; const float* bl2 = (const float*)d_in[12];
  const float* Wr2 = (const float*)d_in[13]; const float* br2 = (const float*)d_in[14];
  const float* We2 = (const float*)d_in[15]; const float* att2 = (const float*)d_in[16];
  const float* bo2 = (const float*)d_in[17];
  const float* Wl3 = (const float*)d_in[18]; const float* bl3 = (const float*)d_in[19];
  const float* Wr3 = (const float*)d_in[20]; const float* br3 = (const float*)d_in[21];
  const float* We3 = (const float*)d_in[22]; const float* att3 = (const float*)d_in[23];
  const float* bo3 = (const float*)d_in[24];
  const float* gn1 = (const float*)d_in[25]; const float* bn1 = (const float*)d_in[26];
  const float* gn2 = (const float*)d_in[27]; const float* bn2 = (const float*)d_in[28];
  const float* gn3 = (const float*)d_in[29]; const float* bn3 = (const float*)d_in[30];
  const float* Pw1 = (const float*)d_in[31]; const float* Pb1 = (const float*)d_in[32];
  const float* Pw2 = (const float*)d_in[33]; const float* Pb2 = (const float*)d_in[34];
  const float* Vw1 = (const float*)d_in[35]; const float* Vb1 = (const float*)d_in[36];
  const float* Vw2 = (const float*)d_in[37]; const float* Vb2 = (const float*)d_in[38];

  const int N = in_sizes[0] / 16;
  const int E = in_sizes[2];
  const int NE = N + E;

  char* w = (char*)d_ws;
  size_t off = 0;
  float* sum_ew = (float*)(w + off); off += 256;
  int* rowptr = (int*)(w + off); off += (size_t)(N + 1)*4; off = (off + 255) & ~(size_t)255;
  int* cursor = (int*)(w + off); off += (size_t)N*4;       off = (off + 255) & ~(size_t)255;
  int* deg    = (int*)(w + off); off += (size_t)N*4;       off = (off + 255) & ~(size_t)255;
  int* csr_src= (int*)(w + off); off += (size_t)NE*4;      off = (off + 255) & ~(size_t)255;
  float* csr_w= (float*)(w + off); off += (size_t)NE*4;    off = (off + 255) & ~(size_t)255;
  // weight bf16 hi/lo planes
  u16* W2lh = (u16*)(w + off); off += (size_t)512*512*2;
  u16* W2ll = (u16*)(w + off); off += (size_t)512*512*2;
  u16* W2rh = (u16*)(w + off); off += (size_t)512*512*2;
  u16* W2rl = (u16*)(w + off); off += (size_t)512*512*2;
  u16* W3lh = (u16*)(w + off); off += (size_t)128*512*2;
  u16* W3ll = (u16*)(w + off); off += (size_t)128*512*2;
  u16* W3rh = (u16*)(w + off); off += (size_t)128*512*2;
  u16* W3rl = (u16*)(w + off); off += (size_t)128*512*2;
  off = (off + 1048575) & ~(size_t)1048575;   // 1MB align for big buffers
  _Float16* A  = (_Float16*)(w + off); off += (size_t)N*512*2;
  _Float16* B  = (_Float16*)(w + off); off += (size_t)N*512*2;
  u16*   Ch = (u16*)(w + off);   off += (size_t)N*512*2;
  u16*   Cl = (u16*)(w + off);   off += (size_t)N*512*2;
  float* D  = (float*)(w + off); off += (size_t)N*128*4;
  (void)ws_size; (void)n_in; (void)out_size;

  hipMemsetAsync(sum_ew, 0, 4, stream);
  hipMemsetAsync(deg, 0, (size_t)N*4, stream);

  k_sum_ew<<<256, 256, 0, stream>>>(ew, E, sum_ew);
  k_deg<<<(E + 255)/256, 256, 0, stream>>>(ei + E, E, deg);
  k_scan<<<1, 1024, 0, stream>>>(deg, rowptr, cursor, N);
  k_scatter<<<(NE + 255)/256, 256, 0, stream>>>(ei, ew, E, N, sum_ew, cursor, csr_src, csr_w);

  // weight splits (small)
  k_split<<<128, 256, 0, stream>>>(Wl2, W2lh, W2ll, 512*512);
  k_split<<<128, 256, 0, stream>>>(Wr2, W2rh, W2rl, 512*512);
  k_split<<<64, 256, 0, stream>>>(Wl3, W3lh, W3ll, 128*512);
  k_split<<<64, 256, 0, stream>>>(Wr3, W3rh, W3rl, 128*512);

  const int GY = (N + 127)/128;

  // Layer 1
  k_lin1<<<N/32, 256, 0, stream>>>(x, Wl1, bl1, Wr1, br1, A, B, N);
  k_agg<4, true, true><<<N, 256, 0, stream>>>(A, B, We1, att1, bo1, gn1, bn1,
                                              rowptr, csr_src, csr_w, nullptr, Ch, Cl, N);
  // Layer 2
  k_gemm_mfma<<<dim3(4, GY), 256, 0, stream>>>(Ch, Cl, W2lh, W2ll, bl2, A, N, 512, 512);
  k_gemm_mfma<<<dim3(4, GY), 256, 0, stream>>>(Ch, Cl, W2rh, W2rl, br2, B, N, 512, 512);
  k_agg<4, true, true><<<N, 256, 0, stream>>>(A, B, We2, att2, bo2, gn2, bn2,
                                              rowptr, csr_src, csr_w, nullptr, Ch, Cl, N);
  // Layer 3
  k_gemm_mfma<<<dim3(1, GY), 256, 0, stream>>>(Ch, Cl, W3lh, W3ll, bl3, A, N, 512, 128);
  k_gemm_mfma<<<dim3(1, GY), 256, 0, stream>>>(Ch, Cl, W3rh, W3rl, br3, B, N, 512, 128);
  k_agg<1, false, false><<<(N + 3)/4, 256, 0, stream>>>(A, B, We3, att3, bo3, gn3, bn3,
                                               rowptr, csr_src, csr_w, D, nullptr, nullptr, N);
  // Heads
  k_heads<<<1, 128, 0, stream>>>(D, nidx, Pw1, Pb1, Pw2, Pb2, Vw1, Vb1, Vw2, Vb2, (float*)d_out);
}

// Round 8
// 681.653 us; speedup vs baseline: 1.1546x; 1.1546x over previous
//
#include <hip/hip_runtime.h>
#include <math.h>

#define NEG_SLOPE 0.2f

typedef unsigned short u16;
typedef unsigned int u32;
typedef __attribute__((ext_vector_type(8))) short bf16x8;
typedef __attribute__((ext_vector_type(8))) _Float16 f16x8;
typedef __attribute__((ext_vector_type(4))) float f32x4;

__device__ __forceinline__ float wave_sum(float v){
  #pragma unroll
  for (int o = 1; o < 64; o <<= 1) v += __shfl_xor(v, o, 64);
  return v;
}

__device__ __forceinline__ u16 f2bf(float f){
  u32 u = __float_as_uint(f);
  return (u16)((u + 0x7FFF + ((u >> 16) & 1)) >> 16);
}
__device__ __forceinline__ float bf2f(u16 h){
  return __uint_as_float(((u32)h) << 16);
}

__device__ __forceinline__ void gl_lds16(const void* g, void* l){
  __builtin_amdgcn_global_load_lds((const __attribute__((address_space(1))) u32*)g,
                                   (__attribute__((address_space(3))) u32*)l, 16, 0, 0);
}

// ---------------- edge-weight mean (sum; divide later) ----------------
__global__ void k_sum_ew(const float* __restrict__ ew, int E, float* __restrict__ out){
  float s = 0.f;
  for (int i = blockIdx.x*blockDim.x + threadIdx.x; i < E; i += gridDim.x*blockDim.x) s += ew[i];
  s = wave_sum(s);
  __shared__ float red[4];
  int lane = threadIdx.x & 63, wid = threadIdx.x >> 6;
  if (lane == 0) red[wid] = s;
  __syncthreads();
  if (threadIdx.x == 0){
    float t = 0.f;
    for (int i = 0; i < (int)(blockDim.x >> 6); i++) t += red[i];
    atomicAdd(out, t);
  }
}

// ---------------- degree histogram (dst) ----------------
__global__ void k_deg(const int* __restrict__ dst, int E, int* __restrict__ deg){
  int i = blockIdx.x*blockDim.x + threadIdx.x;
  if (i < E) atomicAdd(&deg[dst[i]], 1);
}

// ---------------- exclusive scan over N nodes (deg+1 each: self loops) ----------------
__global__ __launch_bounds__(1024) void k_scan(const int* __restrict__ deg, int* __restrict__ rowptr,
                                               int* __restrict__ cursor, int n){
  __shared__ int sums[1024];
  int t = threadIdx.x;
  int CH = (n + 1023) >> 10;
  int base = t*CH;
  int local = 0;
  for (int i = 0; i < CH; i++){ int idx = base + i; if (idx < n) local += deg[idx] + 1; }
  sums[t] = local;
  __syncthreads();
  for (int off = 1; off < 1024; off <<= 1){
    int v = (t >= off) ? sums[t-off] : 0;
    __syncthreads();
    sums[t] += v;
    __syncthreads();
  }
  int run = sums[t] - local;   // exclusive prefix
  for (int i = 0; i < CH; i++){
    int idx = base + i;
    if (idx < n){ rowptr[idx] = run; cursor[idx] = run; run += deg[idx] + 1; }
  }
  if (t == 0) rowptr[n] = sums[1023];
}

// ---------------- scatter edges (+ self loops) into CSR ----------------
__global__ void k_scatter(const int* __restrict__ ei, const float* __restrict__ ew, int E, int n,
                          const float* __restrict__ sum_ew, int* __restrict__ cursor,
                          int* __restrict__ csr_src, float* __restrict__ csr_w){
  int i = blockIdx.x*blockDim.x + threadIdx.x;
  if (i >= E + n) return;
  if (i < E){
    int s = ei[i];         // row 0 = src
    int d = ei[E + i];     // row 1 = dst
    int pos = atomicAdd(&cursor[d], 1);
    csr_src[pos] = s; csr_w[pos] = ew[i];
  } else {
    int v = i - E;
    int pos = atomicAdd(&cursor[v], 1);
    csr_src[pos] = v; csr_w[pos] = (*sum_ew) / (float)E;
  }
}

// ---------------- f32 -> bf16 single (hi) plane ----------------
__global__ void k_split1(const float* __restrict__ in, u16* __restrict__ hi, int m){
  for (int i = blockIdx.x*blockDim.x + threadIdx.x; i < m; i += gridDim.x*blockDim.x)
    hi[i] = f2bf(in[i]);
}

// ---------------- layer-1 linear: x(Nx16) -> xl,xr (Nx512) f16 ----------------
__global__ __launch_bounds__(256) void k_lin1(const float* __restrict__ x,
        const float* __restrict__ Wl, const float* __restrict__ bl,
        const float* __restrict__ Wr, const float* __restrict__ br,
        _Float16* __restrict__ xl, _Float16* __restrict__ xr, int n){
  __shared__ float Ws[16][1028];   // transposed, padded
  __shared__ float bs[1024];
  __shared__ float xs[32][16];
  int t = threadIdx.x;
  for (int i = t; i < 512*16; i += 256){
    int j = i >> 4, k = i & 15;
    Ws[k][j] = Wl[i];
    Ws[k][512 + j] = Wr[i];
  }
  for (int i = t; i < 512; i += 256){ bs[i] = bl[i]; bs[512 + i] = br[i]; }
  int n0 = blockIdx.x * 32;
  for (int i = t; i < 32*16; i += 256){ int r = i >> 4, k = i & 15; xs[r][k] = x[(size_t)(n0 + r)*16 + k]; }
  __syncthreads();
  for (int idx = t; idx < 32*1024; idx += 256){
    int r = idx >> 10, c = idx & 1023;
    float s = bs[c];
    #pragma unroll
    for (int k = 0; k < 16; k++) s += xs[r][k] * Ws[k][c];
    int nn = n0 + r;
    if (c < 512) xl[(size_t)nn*512 + c] = (_Float16)s;
    else         xr[(size_t)nn*512 + (c - 512)] = (_Float16)s;
  }
}

// ---------------- split-A-bf16 x bf16-W MFMA GEMM (2 MFMA terms), fused Wl+Wr ----------------
// side = blockIdx.x / (J/128): 0 -> Wlh/biasl/outl, 1 -> Wrh/biasr/outr.
// A as hi/lo planes; W single bf16 plane (quantization error ~0.1% rel, passes threshold).
__global__ __launch_bounds__(256,4) void k_gemm_mfma(
    const u16* __restrict__ Ah, const u16* __restrict__ Al,
    const u16* __restrict__ Wlh, const u16* __restrict__ Wrh,
    const float* __restrict__ biasl, const float* __restrict__ biasr,
    _Float16* __restrict__ outl, _Float16* __restrict__ outr,
    int n, int K, int J){
  __shared__ __align__(16) u16 lds[12288];   // 24KB: Ah,Al,W planes of 4096 u16
  u16* lA_h = lds;
  u16* lA_l = lds + 4096;
  u16* lW   = lds + 8192;
  int t = threadIdx.x;
  int lane = t & 63, w = t >> 6;
  int lane15 = lane & 15, lgrp = lane >> 4;
  int jb = J >> 7;
  int side = blockIdx.x / jb;
  int j0 = (blockIdx.x - side*jb) * 128;
  const u16* Wh = side ? Wrh : Wlh;
  const float* bias = side ? biasr : biasl;
  _Float16* out = side ? outr : outl;
  int n0 = blockIdx.y * 128;
  int wm = (w >> 1) * 64, wn = (w & 1) * 64;
  f32x4 acc[4][4] = {};

  int s0 = t, s1 = t + 256;
  int r0 = s0 >> 2, r1 = s1 >> 2;
  int sl0 = (s0 & 3) ^ ((r0 >> 1) & 3);
  int sl1 = (s1 & 3) ^ ((r1 >> 1) & 3);
  size_t arow0 = (size_t)min(n0 + r0, n - 1) * K + sl0*8;
  size_t arow1 = (size_t)min(n0 + r1, n - 1) * K + sl1*8;
  size_t wrow0 = (size_t)(j0 + r0) * K + sl0*8;
  size_t wrow1 = (size_t)(j0 + r1) * K + sl1*8;

  int rcol = (lgrp * 16) ^ (((lane15 >> 1) & 3) << 4);

  for (int k0 = 0; k0 < K; k0 += 32){
    gl_lds16(Ah + arow0 + k0, lA_h + s0*8);
    gl_lds16(Ah + arow1 + k0, lA_h + s1*8);
    gl_lds16(Al + arow0 + k0, lA_l + s0*8);
    gl_lds16(Al + arow1 + k0, lA_l + s1*8);
    gl_lds16(Wh + wrow0 + k0, lW + s0*8);
    gl_lds16(Wh + wrow1 + k0, lW + s1*8);
    __syncthreads();
    bf16x8 ah[4], al[4], bh[4];
    #pragma unroll
    for (int i = 0; i < 4; i++){
      int qa = (wm + i*16 + lane15)*64 + rcol;
      ah[i]  = *(const bf16x8*)((const char*)lA_h + qa);
      al[i]  = *(const bf16x8*)((const char*)lA_l + qa);
      int qb = (wn + i*16 + lane15)*64 + rcol;
      bh[i]  = *(const bf16x8*)((const char*)lW + qb);
    }
    #pragma unroll
    for (int mi = 0; mi < 4; mi++)
      #pragma unroll
      for (int ni = 0; ni < 4; ni++){
        acc[mi][ni] = __builtin_amdgcn_mfma_f32_16x16x32_bf16(al[mi], bh[ni], acc[mi][ni], 0, 0, 0);
        acc[mi][ni] = __builtin_amdgcn_mfma_f32_16x16x32_bf16(ah[mi], bh[ni], acc[mi][ni], 0, 0, 0);
      }
    __syncthreads();
  }

  #pragma unroll
  for (int ni = 0; ni < 4; ni++){
    int col = j0 + wn + ni*16 + lane15;
    float bia = bias[col];
    #pragma unroll
    for (int mi = 0; mi < 4; mi++){
      int rowb = n0 + wm + mi*16 + lgrp*4;
      #pragma unroll
      for (int rg = 0; rg < 4; rg++){
        int row = rowb + rg;
        if (row < n) out[(size_t)row*J + col] = (_Float16)(acc[mi][ni][rg] + bia);
      }
    }
  }
}

// ---------------- GATv2 edge-softmax + aggregation + bias + LayerNorm (+ELU) ----------------
// HEADS==4: NB nodes per block sequentially (4 waves = 4 heads); NB=2 amortizes the
// per-wave param preamble while keeping 10000 blocks (>> 2048 resident, no tail cliff).
// HEADS==1: 4 nodes per block, one per wave, NB=1. Within a wave: 4 groups x 16 lanes;
// each group processes TWO edges per iteration. Defer-max online softmax (THR=8).
// ELU via __expf-1 (no expm1 libcall).
template<int HEADS, bool DO_ELU, bool EMIT, int NB>
__global__ __launch_bounds__(256) void k_agg(
                      const _Float16* __restrict__ xl, const _Float16* __restrict__ xr,
                      const float* __restrict__ We, const float* __restrict__ att, const float* __restrict__ bo,
                      const float* __restrict__ gam, const float* __restrict__ bet,
                      const int* __restrict__ rowptr, const int* __restrict__ csr_src,
                      const float* __restrict__ csr_w,
                      float* __restrict__ out, u16* __restrict__ oh, u16* __restrict__ ol, int n){
  constexpr int HC_ = HEADS * 128;
  constexpr float RT = 8.f;
  int t = threadIdx.x, lane = t & 63, w = t >> 6;
  int l16 = lane & 15, grp = lane >> 4;
  int h = (HEADS == 4) ? w : 0;
  int c0 = h*128 + l16*8;          // 8 channels per lane

  // hoisted per-layer params (amortized over NB nodes)
  float4 wea = *(const float4*)&We[c0],  web = *(const float4*)&We[c0 + 4];
  float4 ata = *(const float4*)&att[c0], atb = *(const float4*)&att[c0 + 4];
  float4 boa = *(const float4*)&bo[c0],  bob = *(const float4*)&bo[c0 + 4];
  float4 ga  = *(const float4*)&gam[c0], gb  = *(const float4*)&gam[c0 + 4];
  float4 ba  = *(const float4*)&bet[c0], bb  = *(const float4*)&bet[c0 + 4];
  float we8[8] = {wea.x,wea.y,wea.z,wea.w,web.x,web.y,web.z,web.w};
  float at8[8] = {ata.x,ata.y,ata.z,ata.w,atb.x,atb.y,atb.z,atb.w};
  float bo8[8] = {boa.x,boa.y,boa.z,boa.w,bob.x,bob.y,bob.z,bob.w};
  float g8[8]  = {ga.x,ga.y,ga.z,ga.w,gb.x,gb.y,gb.z,gb.w};
  float b8[8]  = {ba.x,ba.y,ba.z,ba.w,bb.x,bb.y,bb.z,bb.w};

  __shared__ float red[4][2];

  #pragma unroll
  for (int ib = 0; ib < NB; ib++){
    int nid = (HEADS == 4) ? blockIdx.x*NB + ib : blockIdx.x*4 + w;
    if (nid >= n) break;           // block-uniform for HEADS==4

    f16x8 xrh = *(const f16x8*)(xr + (size_t)nid*HC_ + c0);
    float xr8[8];
    #pragma unroll
    for (int j = 0; j < 8; j++) xr8[j] = (float)xrh[j];

    int rs = rowptr[nid], re = rowptr[nid + 1];
    float m = -3e38f, d = 0.f;
    float acc[8] = {};
    for (int e0 = rs + grp; e0 < re; e0 += 8){
      int e1 = e0 + 4;
      bool has1 = e1 < re;
      int s0 = csr_src[e0];
      int s1 = has1 ? csr_src[e1] : s0;
      float w0 = csr_w[e0];
      float w1 = has1 ? csr_w[e1] : 0.f;
      f16x8 hv0 = *(const f16x8*)(xl + (size_t)s0*HC_ + c0);
      f16x8 hv1 = *(const f16x8*)(xl + (size_t)s1*HC_ + c0);
      float v0[8], v1[8];
      #pragma unroll
      for (int j = 0; j < 8; j++){ v0[j] = (float)hv0[j]; v1[j] = (float)hv1[j]; }
      float p0 = 0.f, p1 = 0.f;
      #pragma unroll
      for (int j = 0; j < 8; j++){
        float tv0 = v0[j] + xr8[j] + w0*we8[j];
        tv0 = (tv0 > 0.f) ? tv0 : NEG_SLOPE*tv0;
        p0 += tv0 * at8[j];
        float tv1 = v1[j] + xr8[j] + w1*we8[j];
        tv1 = (tv1 > 0.f) ? tv1 : NEG_SLOPE*tv1;
        p1 += tv1 * at8[j];
      }
      #pragma unroll
      for (int o = 1; o < 16; o <<= 1){
        p0 += __shfl_xor(p0, o, 64);
        p1 += __shfl_xor(p1, o, 64);
      }
      if (!has1) p1 = -3e38f;
      float pm = fmaxf(p0, p1);
      if (pm > m + RT){          // rare rescale (defer-max)
        float sc = __expf(m - pm);
        d *= sc;
        #pragma unroll
        for (int j = 0; j < 8; j++) acc[j] *= sc;
        m = pm;
      }
      float e0x = __expf(p0 - m), e1x = __expf(p1 - m);
      d += e0x + e1x;
      #pragma unroll
      for (int j = 0; j < 8; j++) acc[j] += e0x*v0[j] + e1x*v1[j];
    }
    // merge the 4 groups' online states (xor masks 16, 32)
    float M = m;
    M = fmaxf(M, __shfl_xor(M, 16, 64));
    M = fmaxf(M, __shfl_xor(M, 32, 64));
    float sc = __expf(m - M);
    float dd = d * sc;
    dd += __shfl_xor(dd, 16, 64);
    dd += __shfl_xor(dd, 32, 64);
    #pragma unroll
    for (int j = 0; j < 8; j++){
      float a = acc[j] * sc;
      a += __shfl_xor(a, 16, 64);
      a += __shfl_xor(a, 32, 64);
      acc[j] = a;
    }
    float inv = 1.f / (dd + 1e-16f);
    float o8[8];
    #pragma unroll
    for (int j = 0; j < 8; j++) o8[j] = acc[j]*inv + bo8[j];

    // LayerNorm over HC_ channels
    float s1 = 0.f, s2 = 0.f;
    #pragma unroll
    for (int j = 0; j < 8; j++){ s1 += o8[j]; s2 += o8[j]*o8[j]; }
    #pragma unroll
    for (int o = 1; o < 16; o <<= 1){ s1 += __shfl_xor(s1, o, 64); s2 += __shfl_xor(s2, o, 64); }
    float S1, S2;
    if (HEADS == 4){
      if (NB > 1) __syncthreads();         // WAR guard on red[] across node iters
      if (lane == 0){ red[w][0] = s1; red[w][1] = s2; }
      __syncthreads();
      S1 = red[0][0] + red[1][0] + red[2][0] + red[3][0];
      S2 = red[0][1] + red[1][1] + red[2][1] + red[3][1];
    } else {
      S1 = s1; S2 = s2;
    }
    float mu = S1 / (float)HC_;
    float var = S2 / (float)HC_ - mu*mu;
    float rstd = rsqrtf(var + 1e-5f);
    float y[8];
    #pragma unroll
    for (int j = 0; j < 8; j++){
      float yy = (o8[j] - mu)*rstd*g8[j] + b8[j];
      if (DO_ELU) yy = (yy > 0.f) ? yy : (__expf(yy) - 1.f);
      y[j] = yy;
    }
    if (grp == 0){
      if (EMIT){
        u32 hv2[4], lv2[4];
        #pragma unroll
        for (int j = 0; j < 4; j++){
          u16 h0 = f2bf(y[2*j]), h1 = f2bf(y[2*j+1]);
          u16 l0 = f2bf(y[2*j] - bf2f(h0)), l1 = f2bf(y[2*j+1] - bf2f(h1));
          hv2[j] = (u32)h0 | ((u32)h1 << 16);
          lv2[j] = (u32)l0 | ((u32)l1 << 16);
        }
        *(uint4*)&oh[(size_t)nid*HC_ + c0] = make_uint4(hv2[0],hv2[1],hv2[2],hv2[3]);
        *(uint4*)&ol[(size_t)nid*HC_ + c0] = make_uint4(lv2[0],lv2[1],lv2[2],lv2[3]);
      } else {
        float* orow = out + (size_t)nid*HC_ + c0;
        *(float4*)orow       = make_float4(y[0],y[1],y[2],y[3]);
        *(float4*)(orow + 4) = make_float4(y[4],y[5],y[6],y[7]);
      }
    }
  }
}

// ---------------- policy/value heads on one node ----------------
__global__ __launch_bounds__(128) void k_heads(const float* __restrict__ h3, const int* __restrict__ idxp,
        const float* __restrict__ Pw1, const float* __restrict__ Pb1,
        const float* __restrict__ Pw2, const float* __restrict__ Pb2,
        const float* __restrict__ Vw1, const float* __restrict__ Vb1,
        const float* __restrict__ Vw2, const float* __restrict__ Vb2,
        float* __restrict__ out){
  __shared__ float z[128], hp[128], hv[128];
  int t = threadIdx.x;
  int idx = *idxp;
  z[t] = h3[(size_t)idx*128 + t];
  __syncthreads();
  float sp = Pb1[t], sv = Vb1[t];
  for (int c = 0; c < 128; c++){
    float zc = z[c];
    sp += Pw1[t*128 + c] * zc;
    sv += Vw1[t*128 + c] * zc;
  }
  hp[t] = fmaxf(sp, 0.f);
  hv[t] = fmaxf(sv, 0.f);
  __syncthreads();
  if (t < 64){
    float l0 = Pw2[t]*hp[t]       + Pw2[64 + t]*hp[64 + t];
    float l1 = Pw2[128 + t]*hp[t] + Pw2[192 + t]*hp[64 + t];
    float vv = Vw2[t]*hv[t]       + Vw2[64 + t]*hv[64 + t];
    #pragma unroll
    for (int o = 1; o < 64; o <<= 1){
      l0 += __shfl_xor(l0, o, 64); l1 += __shfl_xor(l1, o, 64); vv += __shfl_xor(vv, o, 64);
    }
    if (t == 0){ out[0] = l0 + Pb2[0]; out[1] = l1 + Pb2[1]; out[2] = vv + Vb2[0]; }
  }
}

extern "C" void kernel_launch(void* const* d_in, const int* in_sizes, int n_in,
                              void* d_out, int out_size, void* d_ws, size_t ws_size,
                              hipStream_t stream){
  const float* x    = (const float*)d_in[0];
  const int*   ei   = (const int*)d_in[1];
  const float* ew   = (const float*)d_in[2];
  const int*   nidx = (const int*)d_in[3];
  const float* Wl1 = (const float*)d_in[4];  const float* bl1 = (const float*)d_in[5];
  const float* Wr1 = (const float*)d_in[6];  const float* br1 = (const float*)d_in[7];
  const float* We1 = (const float*)d_in[8];  const float* att1 = (const float*)d_in[9];
  const float* bo1 = (const float*)d_in[10];
  const float* Wl2 = (const float*)d_in[11]; const float* bl2 = (const float*)d_in[12];
  const float* Wr2 = (const float*)d_in[13]; const float* br2 = (const float*)d_in[14];
  const float* We2 = (const float*)d_in[15]; const float* att2 = (const float*)d_in[16];
  const float* bo2 = (const float*)d_in[17];
  const float* Wl3 = (const float*)d_in[18]; const float* bl3 = (const float*)d_in[19];
  const float* Wr3 = (const float*)d_in[20]; const float* br3 = (const float*)d_in[21];
  const float* We3 = (const float*)d_in[22]; const float* att3 = (const float*)d_in[23];
  const float* bo3 = (const float*)d_in[24];
  const float* gn1 = (const float*)d_in[25]; const float* bn1 = (const float*)d_in[26];
  const float* gn2 = (const float*)d_in[27]; const float* bn2 = (const float*)d_in[28];
  const float* gn3 = (const float*)d_in[29]; const float* bn3 = (const float*)d_in[30];
  const float* Pw1 = (const float*)d_in[31]; const float* Pb1 = (const float*)d_in[32];
  const float* Pw2 = (const float*)d_in[33]; const float* Pb2 = (const float*)d_in[34];
  const float* Vw1 = (const float*)d_in[35]; const float* Vb1 = (const float*)d_in[36];
  const float* Vw2 = (const float*)d_in[37]; const float* Vb2 = (const float*)d_in[38];

  const int N = in_sizes[0] / 16;
  const int E = in_sizes[2];
  const int NE = N + E;

  char* w = (char*)d_ws;
  size_t off = 0;
  float* sum_ew = (float*)(w + off); off += 256;
  int* rowptr = (int*)(w + off); off += (size_t)(N + 1)*4; off = (off + 255) & ~(size_t)255;
  int* cursor = (int*)(w + off); off += (size_t)N*4;       off = (off + 255) & ~(size_t)255;
  int* deg    = (int*)(w + off); off += (size_t)N*4;       off = (off + 255) & ~(size_t)255;
  int* csr_src= (int*)(w + off); off += (size_t)NE*4;      off = (off + 255) & ~(size_t)255;
  float* csr_w= (float*)(w + off); off += (size_t)NE*4;    off = (off + 255) & ~(size_t)255;
  // weight bf16 planes (single hi plane each)
  u16* W2lh = (u16*)(w + off); off += (size_t)512*512*2;
  u16* W2rh = (u16*)(w + off); off += (size_t)512*512*2;
  u16* W3lh = (u16*)(w + off); off += (size_t)128*512*2;
  u16* W3rh = (u16*)(w + off); off += (size_t)128*512*2;
  off = (off + 1048575) & ~(size_t)1048575;   // 1MB align for big buffers
  _Float16* A  = (_Float16*)(w + off); off += (size_t)N*512*2;
  _Float16* B  = (_Float16*)(w + off); off += (size_t)N*512*2;
  u16*   Ch = (u16*)(w + off);   off += (size_t)N*512*2;
  u16*   Cl = (u16*)(w + off);   off += (size_t)N*512*2;
  float* D  = (float*)(w + off); off += (size_t)N*128*4;
  (void)ws_size; (void)n_in; (void)out_size;

  hipMemsetAsync(sum_ew, 0, 4, stream);
  hipMemsetAsync(deg, 0, (size_t)N*4, stream);

  k_sum_ew<<<256, 256, 0, stream>>>(ew, E, sum_ew);
  k_deg<<<(E + 255)/256, 256, 0, stream>>>(ei + E, E, deg);
  k_scan<<<1, 1024, 0, stream>>>(deg, rowptr, cursor, N);
  k_scatter<<<(NE + 255)/256, 256, 0, stream>>>(ei, ew, E, N, sum_ew, cursor, csr_src, csr_w);

  // weight bf16 planes (small)
  k_split1<<<128, 256, 0, stream>>>(Wl2, W2lh, 512*512);
  k_split1<<<128, 256, 0, stream>>>(Wr2, W2rh, 512*512);
  k_split1<<<64, 256, 0, stream>>>(Wl3, W3lh, 128*512);
  k_split1<<<64, 256, 0, stream>>>(Wr3, W3rh, 128*512);

  const int GY = (N + 127)/128;

  // Layer 1
  k_lin1<<<N/32, 256, 0, stream>>>(x, Wl1, bl1, Wr1, br1, A, B, N);
  k_agg<4, true, true, 2><<<(N + 1)/2, 256, 0, stream>>>(A, B, We1, att1, bo1, gn1, bn1,
                                              rowptr, csr_src, csr_w, nullptr, Ch, Cl, N);
  // Layer 2 (fused Wl+Wr dispatch)
  k_gemm_mfma<<<dim3(8, GY), 256, 0, stream>>>(Ch, Cl, W2lh, W2rh, bl2, br2, A, B, N, 512, 512);
  k_agg<4, true, true, 2><<<(N + 1)/2, 256, 0, stream>>>(A, B, We2, att2, bo2, gn2, bn2,
                                              rowptr, csr_src, csr_w, nullptr, Ch, Cl, N);
  // Layer 3 (fused)
  k_gemm_mfma<<<dim3(2, GY), 256, 0, stream>>>(Ch, Cl, W3lh, W3rh, bl3, br3, A, B, N, 512, 128);
  k_agg<1, false, false, 1><<<(N + 3)/4, 256, 0, stream>>>(A, B, We3, att3, bo3, gn3, bn3,
                                               rowptr, csr_src, csr_w, D, nullptr, nullptr, N);
  // Heads
  k_heads<<<1, 128, 0, stream>>>(D, nidx, Pw1, Pb1, Pw2, Pb2, Vw1, Vb1, Vw2, Vb2, (float*)d_out);
}

// Round 10
// 639.461 us; speedup vs baseline: 1.2308x; 1.0660x over previous
//
#include <hip/hip_runtime.h>
#include <math.h>

#define NEG_SLOPE 0.2f

typedef unsigned short u16;
typedef unsigned int u32;
typedef __attribute__((ext_vector_type(8))) short bf16x8;
typedef __attribute__((ext_vector_type(8))) _Float16 f16x8;
typedef __attribute__((ext_vector_type(2))) _Float16 f16x2;
typedef __attribute__((ext_vector_type(4))) float f32x4;

__device__ __forceinline__ float wave_sum(float v){
  #pragma unroll
  for (int o = 1; o < 64; o <<= 1) v += __shfl_xor(v, o, 64);
  return v;
}

__device__ __forceinline__ u16 f2bf(float f){
  u32 u = __float_as_uint(f);
  return (u16)((u + 0x7FFF + ((u >> 16) & 1)) >> 16);
}
__device__ __forceinline__ float bf2f(u16 h){
  return __uint_as_float(((u32)h) << 16);
}

__device__ __forceinline__ void gl_lds16(const void* g, void* l){
  __builtin_amdgcn_global_load_lds((const __attribute__((address_space(1))) u32*)g,
                                   (__attribute__((address_space(3))) u32*)l, 16, 0, 0);
}

// alpha contribution of 8 channels: dot(leaky(v + xr + w*we), att) in packed f16
__device__ __forceinline__ float alpha8(f16x8 hv, f16x8 xrh, _Float16 wh, f16x8 weh, f16x8 ath){
  f16x8 tv = hv + xrh + weh*wh;
  f16x8 zero = {0,0,0,0,0,0,0,0};
  f16x8 pos = __builtin_elementwise_max(tv, zero);
  f16x8 neg = __builtin_elementwise_min(tv, zero);
  f16x8 lk  = pos + neg*(_Float16)NEG_SLOPE;
  float p = 0.f;
#if __has_builtin(__builtin_amdgcn_fdot2)
  #pragma unroll
  for (int i = 0; i < 4; i++){
    f16x2 a = {lk[2*i], lk[2*i+1]};
    f16x2 b = {ath[2*i], ath[2*i+1]};
    p = __builtin_amdgcn_fdot2(a, b, p, false);
  }
#else
  #pragma unroll
  for (int j = 0; j < 8; j++) p += (float)lk[j]*(float)ath[j];
#endif
  return p;
}

// ---------------- fused: degree histogram (dst) + edge-weight sum ----------------
__global__ void k_prep(const int* __restrict__ dst, const float* __restrict__ ew, int E,
                       int* __restrict__ deg, float* __restrict__ sum_ew){
  float s = 0.f;
  for (int i = blockIdx.x*blockDim.x + threadIdx.x; i < E; i += gridDim.x*blockDim.x){
    atomicAdd(&deg[dst[i]], 1);
    s += ew[i];
  }
  s = wave_sum(s);
  __shared__ float red[4];
  int lane = threadIdx.x & 63, wid = threadIdx.x >> 6;
  if (lane == 0) red[wid] = s;
  __syncthreads();
  if (threadIdx.x == 0){
    float t = 0.f;
    for (int i = 0; i < (int)(blockDim.x >> 6); i++) t += red[i];
    atomicAdd(sum_ew, t);
  }
}

// ---------------- exclusive scan over N nodes (deg+1 each: self loops) ----------------
__global__ __launch_bounds__(1024) void k_scan(const int* __restrict__ deg, int* __restrict__ rowptr,
                                               int* __restrict__ cursor, int n){
  __shared__ int sums[1024];
  int t = threadIdx.x;
  int CH = (n + 1023) >> 10;
  int base = t*CH;
  int local = 0;
  for (int i = 0; i < CH; i++){ int idx = base + i; if (idx < n) local += deg[idx] + 1; }
  sums[t] = local;
  __syncthreads();
  for (int off = 1; off < 1024; off <<= 1){
    int v = (t >= off) ? sums[t-off] : 0;
    __syncthreads();
    sums[t] += v;
    __syncthreads();
  }
  int run = sums[t] - local;   // exclusive prefix
  for (int i = 0; i < CH; i++){
    int idx = base + i;
    if (idx < n){ rowptr[idx] = run; cursor[idx] = run; run += deg[idx] + 1; }
  }
  if (t == 0) rowptr[n] = sums[1023];
}

// ---------------- scatter edges (+ self loops) into CSR ----------------
__global__ void k_scatter(const int* __restrict__ ei, const float* __restrict__ ew, int E, int n,
                          const float* __restrict__ sum_ew, int* __restrict__ cursor,
                          int* __restrict__ csr_src, float* __restrict__ csr_w){
  int i = blockIdx.x*blockDim.x + threadIdx.x;
  if (i >= E + n) return;
  if (i < E){
    int s = ei[i];         // row 0 = src
    int d = ei[E + i];     // row 1 = dst
    int pos = atomicAdd(&cursor[d], 1);
    csr_src[pos] = s; csr_w[pos] = ew[i];
  } else {
    int v = i - E;
    int pos = atomicAdd(&cursor[v], 1);
    csr_src[pos] = v; csr_w[pos] = (*sum_ew) / (float)E;
  }
}

// ---------------- all 4 weight planes f32->bf16 in one kernel ----------------
__global__ void k_splitW(const float* __restrict__ Wl2, const float* __restrict__ Wr2,
                         const float* __restrict__ Wl3, const float* __restrict__ Wr3,
                         u16* __restrict__ W2lh, u16* __restrict__ W2rh,
                         u16* __restrict__ W3lh, u16* __restrict__ W3rh){
  int i = blockIdx.x*blockDim.x + threadIdx.x;       // grid covers 655360
  if (i < 262144)      W2lh[i]          = f2bf(Wl2[i]);
  else if (i < 524288) W2rh[i - 262144] = f2bf(Wr2[i - 262144]);
  else if (i < 589824) W3lh[i - 524288] = f2bf(Wl3[i - 524288]);
  else if (i < 655360) W3rh[i - 589824] = f2bf(Wr3[i - 589824]);
}

// ---------------- layer-1 linear: x(Nx16) -> xl,xr (Nx512) f16 ----------------
__global__ __launch_bounds__(256) void k_lin1(const float* __restrict__ x,
        const float* __restrict__ Wl, const float* __restrict__ bl,
        const float* __restrict__ Wr, const float* __restrict__ br,
        _Float16* __restrict__ xl, _Float16* __restrict__ xr, int n){
  __shared__ float Ws[16][1028];   // transposed, padded
  __shared__ float bs[1024];
  __shared__ float xs[32][16];
  int t = threadIdx.x;
  for (int i = t; i < 512*16; i += 256){
    int j = i >> 4, k = i & 15;
    Ws[k][j] = Wl[i];
    Ws[k][512 + j] = Wr[i];
  }
  for (int i = t; i < 512; i += 256){ bs[i] = bl[i]; bs[512 + i] = br[i]; }
  int n0 = blockIdx.x * 32;
  for (int i = t; i < 32*16; i += 256){ int r = i >> 4, k = i & 15; xs[r][k] = x[(size_t)(n0 + r)*16 + k]; }
  __syncthreads();
  for (int idx = t; idx < 32*1024; idx += 256){
    int r = idx >> 10, c = idx & 1023;
    float s = bs[c];
    #pragma unroll
    for (int k = 0; k < 16; k++) s += xs[r][k] * Ws[k][c];
    int nn = n0 + r;
    if (c < 512) xl[(size_t)nn*512 + c] = (_Float16)s;
    else         xr[(size_t)nn*512 + (c - 512)] = (_Float16)s;
  }
}

// ---------------- split-A-bf16 x bf16-W MFMA GEMM (2 MFMA terms), fused Wl+Wr ----------------
__global__ __launch_bounds__(256,4) void k_gemm_mfma(
    const u16* __restrict__ Ah, const u16* __restrict__ Al,
    const u16* __restrict__ Wlh, const u16* __restrict__ Wrh,
    const float* __restrict__ biasl, const float* __restrict__ biasr,
    _Float16* __restrict__ outl, _Float16* __restrict__ outr,
    int n, int K, int J){
  __shared__ __align__(16) u16 lds[12288];   // 24KB: Ah,Al,W planes of 4096 u16
  u16* lA_h = lds;
  u16* lA_l = lds + 4096;
  u16* lW   = lds + 8192;
  int t = threadIdx.x;
  int lane = t & 63, w = t >> 6;
  int lane15 = lane & 15, lgrp = lane >> 4;
  int jb = J >> 7;
  int side = blockIdx.x / jb;
  int j0 = (blockIdx.x - side*jb) * 128;
  const u16* Wh = side ? Wrh : Wlh;
  const float* bias = side ? biasr : biasl;
  _Float16* out = side ? outr : outl;
  int n0 = blockIdx.y * 128;
  int wm = (w >> 1) * 64, wn = (w & 1) * 64;
  f32x4 acc[4][4] = {};

  int s0 = t, s1 = t + 256;
  int r0 = s0 >> 2, r1 = s1 >> 2;
  int sl0 = (s0 & 3) ^ ((r0 >> 1) & 3);
  int sl1 = (s1 & 3) ^ ((r1 >> 1) & 3);
  size_t arow0 = (size_t)min(n0 + r0, n - 1) * K + sl0*8;
  size_t arow1 = (size_t)min(n0 + r1, n - 1) * K + sl1*8;
  size_t wrow0 = (size_t)(j0 + r0) * K + sl0*8;
  size_t wrow1 = (size_t)(j0 + r1) * K + sl1*8;

  int rcol = (lgrp * 16) ^ (((lane15 >> 1) & 3) << 4);

  for (int k0 = 0; k0 < K; k0 += 32){
    gl_lds16(Ah + arow0 + k0, lA_h + s0*8);
    gl_lds16(Ah + arow1 + k0, lA_h + s1*8);
    gl_lds16(Al + arow0 + k0, lA_l + s0*8);
    gl_lds16(Al + arow1 + k0, lA_l + s1*8);
    gl_lds16(Wh + wrow0 + k0, lW + s0*8);
    gl_lds16(Wh + wrow1 + k0, lW + s1*8);
    __syncthreads();
    bf16x8 ah[4], al[4], bh[4];
    #pragma unroll
    for (int i = 0; i < 4; i++){
      int qa = (wm + i*16 + lane15)*64 + rcol;
      ah[i]  = *(const bf16x8*)((const char*)lA_h + qa);
      al[i]  = *(const bf16x8*)((const char*)lA_l + qa);
      int qb = (wn + i*16 + lane15)*64 + rcol;
      bh[i]  = *(const bf16x8*)((const char*)lW + qb);
    }
    #pragma unroll
    for (int mi = 0; mi < 4; mi++)
      #pragma unroll
      for (int ni = 0; ni < 4; ni++){
        acc[mi][ni] = __builtin_amdgcn_mfma_f32_16x16x32_bf16(al[mi], bh[ni], acc[mi][ni], 0, 0, 0);
        acc[mi][ni] = __builtin_amdgcn_mfma_f32_16x16x32_bf16(ah[mi], bh[ni], acc[mi][ni], 0, 0, 0);
      }
    __syncthreads();
  }

  #pragma unroll
  for (int ni = 0; ni < 4; ni++){
    int col = j0 + wn + ni*16 + lane15;
    float bia = bias[col];
    #pragma unroll
    for (int mi = 0; mi < 4; mi++){
      int rowb = n0 + wm + mi*16 + lgrp*4;
      #pragma unroll
      for (int rg = 0; rg < 4; rg++){
        int row = rowb + rg;
        if (row < n) out[(size_t)row*J + col] = (_Float16)(acc[mi][ni][rg] + bia);
      }
    }
  }
}

// ---------------- GATv2 4-head agg + bias + LayerNorm + ELU, emit hi/lo bf16 ----------------
// Block = 4 waves = 4 heads; NB=4 nodes sequential per block (5000 blocks).
// Per wave: 4 groups x 16 lanes split the node's edges, 2-edge unroll.
// Packed-f16 alpha math; f32 online softmax + accumulation. Defer-max THR=8.
__global__ __launch_bounds__(256) void k_agg4(
                      const _Float16* __restrict__ xl, const _Float16* __restrict__ xr,
                      const float* __restrict__ We, const float* __restrict__ att, const float* __restrict__ bo,
                      const float* __restrict__ gam, const float* __restrict__ bet,
                      const int* __restrict__ rowptr, const int* __restrict__ csr_src,
                      const float* __restrict__ csr_w,
                      u16* __restrict__ oh, u16* __restrict__ ol, int n){
  constexpr int HC_ = 512;
  constexpr float RT = 8.f;
  constexpr int NB = 4;
  int t = threadIdx.x, lane = t & 63, w = t >> 6;
  int l16 = lane & 15, grp = lane >> 4;
  int c0 = w*128 + l16*8;          // 8 channels per lane

  // hoisted per-layer params
  float4 wea = *(const float4*)&We[c0],  web = *(const float4*)&We[c0 + 4];
  float4 ata = *(const float4*)&att[c0], atb = *(const float4*)&att[c0 + 4];
  float4 boa = *(const float4*)&bo[c0],  bob = *(const float4*)&bo[c0 + 4];
  float4 ga  = *(const float4*)&gam[c0], gb  = *(const float4*)&gam[c0 + 4];
  float4 ba  = *(const float4*)&bet[c0], bb  = *(const float4*)&bet[c0 + 4];
  float we8[8] = {wea.x,wea.y,wea.z,wea.w,web.x,web.y,web.z,web.w};
  float at8[8] = {ata.x,ata.y,ata.z,ata.w,atb.x,atb.y,atb.z,atb.w};
  float bo8[8] = {boa.x,boa.y,boa.z,boa.w,bob.x,bob.y,bob.z,bob.w};
  float g8[8]  = {ga.x,ga.y,ga.z,ga.w,gb.x,gb.y,gb.z,gb.w};
  float b8[8]  = {ba.x,ba.y,ba.z,ba.w,bb.x,bb.y,bb.z,bb.w};
  f16x8 weh, ath;
  #pragma unroll
  for (int j = 0; j < 8; j++){ weh[j] = (_Float16)we8[j]; ath[j] = (_Float16)at8[j]; }

  __shared__ float red[4][2];

  #pragma unroll 1
  for (int ib = 0; ib < NB; ib++){
    int nid = blockIdx.x*NB + ib;
    if (nid >= n) break;           // block-uniform

    f16x8 xrh = *(const f16x8*)(xr + (size_t)nid*HC_ + c0);

    int rs = rowptr[nid], re = rowptr[nid + 1];
    float m = -3e38f, d = 0.f;
    float acc[8] = {};
    for (int e0 = rs + grp; e0 < re; e0 += 8){
      int e1 = e0 + 4;
      bool has1 = e1 < re;
      int s0 = csr_src[e0];
      int s1 = has1 ? csr_src[e1] : s0;
      float w0 = csr_w[e0];
      float w1 = has1 ? csr_w[e1] : 0.f;
      f16x8 hv0 = *(const f16x8*)(xl + (size_t)s0*HC_ + c0);
      f16x8 hv1 = *(const f16x8*)(xl + (size_t)s1*HC_ + c0);
      float p0 = alpha8(hv0, xrh, (_Float16)w0, weh, ath);
      float p1 = alpha8(hv1, xrh, (_Float16)w1, weh, ath);
      #pragma unroll
      for (int o = 1; o < 16; o <<= 1){
        p0 += __shfl_xor(p0, o, 64);
        p1 += __shfl_xor(p1, o, 64);
      }
      if (!has1) p1 = -3e38f;
      float pm = fmaxf(p0, p1);
      if (pm > m + RT){          // rare rescale (defer-max)
        float sc = __expf(m - pm);
        d *= sc;
        #pragma unroll
        for (int j = 0; j < 8; j++) acc[j] *= sc;
        m = pm;
      }
      float e0x = __expf(p0 - m), e1x = __expf(p1 - m);
      d += e0x + e1x;
      float v0[8], v1[8];
      #pragma unroll
      for (int j = 0; j < 8; j++){ v0[j] = (float)hv0[j]; v1[j] = (float)hv1[j]; }
      #pragma unroll
      for (int j = 0; j < 8; j++) acc[j] += e0x*v0[j] + e1x*v1[j];
    }
    // merge the 4 groups' online states (xor masks 16, 32)
    float M = m;
    M = fmaxf(M, __shfl_xor(M, 16, 64));
    M = fmaxf(M, __shfl_xor(M, 32, 64));
    float sc = __expf(m - M);
    float dd = d * sc;
    dd += __shfl_xor(dd, 16, 64);
    dd += __shfl_xor(dd, 32, 64);
    #pragma unroll
    for (int j = 0; j < 8; j++){
      float a = acc[j] * sc;
      a += __shfl_xor(a, 16, 64);
      a += __shfl_xor(a, 32, 64);
      acc[j] = a;
    }
    float inv = 1.f / (dd + 1e-16f);
    float o8[8];
    #pragma unroll
    for (int j = 0; j < 8; j++) o8[j] = acc[j]*inv + bo8[j];

    // LayerNorm over 512 channels
    float s1 = 0.f, s2 = 0.f;
    #pragma unroll
    for (int j = 0; j < 8; j++){ s1 += o8[j]; s2 += o8[j]*o8[j]; }
    #pragma unroll
    for (int o = 1; o < 16; o <<= 1){ s1 += __shfl_xor(s1, o, 64); s2 += __shfl_xor(s2, o, 64); }
    __syncthreads();                       // WAR guard on red[] across node iters
    if (lane == 0){ red[w][0] = s1; red[w][1] = s2; }
    __syncthreads();
    float S1 = red[0][0] + red[1][0] + red[2][0] + red[3][0];
    float S2 = red[0][1] + red[1][1] + red[2][1] + red[3][1];
    float mu = S1 / (float)HC_;
    float var = S2 / (float)HC_ - mu*mu;
    float rstd = rsqrtf(var + 1e-5f);
    float y[8];
    #pragma unroll
    for (int j = 0; j < 8; j++){
      float yy = (o8[j] - mu)*rstd*g8[j] + b8[j];
      y[j] = (yy > 0.f) ? yy : (__expf(yy) - 1.f);   // ELU
    }
    if (grp == 0){
      u32 hv2[4], lv2[4];
      #pragma unroll
      for (int j = 0; j < 4; j++){
        u16 h0 = f2bf(y[2*j]), h1 = f2bf(y[2*j+1]);
        u16 l0 = f2bf(y[2*j] - bf2f(h0)), l1 = f2bf(y[2*j+1] - bf2f(h1));
        hv2[j] = (u32)h0 | ((u32)h1 << 16);
        lv2[j] = (u32)l0 | ((u32)l1 << 16);
      }
      *(uint4*)&oh[(size_t)nid*HC_ + c0] = make_uint4(hv2[0],hv2[1],hv2[2],hv2[3]);
      *(uint4*)&ol[(size_t)nid*HC_ + c0] = make_uint4(lv2[0],lv2[1],lv2[2],lv2[3]);
    }
  }
}

// ---------------- layer-3 agg (1 head, no ELU, f32 out): one node per 16-lane group ----------------
// 64-thread blocks; wave = 4 groups = 4 nodes. No cross-group merge; LN group-local.
__global__ __launch_bounds__(64) void k_agg1(
                      const _Float16* __restrict__ xl, const _Float16* __restrict__ xr,
                      const float* __restrict__ We, const float* __restrict__ att, const float* __restrict__ bo,
                      const float* __restrict__ gam, const float* __restrict__ bet,
                      const int* __restrict__ rowptr, const int* __restrict__ csr_src,
                      const float* __restrict__ csr_w,
                      float* __restrict__ out, int n){
  constexpr float RT = 8.f;
  int lane = threadIdx.x;
  int l16 = lane & 15, grp = lane >> 4;
  int c0 = l16*8;

  float4 wea = *(const float4*)&We[c0],  web = *(const float4*)&We[c0 + 4];
  float4 ata = *(const float4*)&att[c0], atb = *(const float4*)&att[c0 + 4];
  float4 boa = *(const float4*)&bo[c0],  bob = *(const float4*)&bo[c0 + 4];
  float4 ga  = *(const float4*)&gam[c0], gb  = *(const float4*)&gam[c0 + 4];
  float4 ba  = *(const float4*)&bet[c0], bb  = *(const float4*)&bet[c0 + 4];
  float we8[8] = {wea.x,wea.y,wea.z,wea.w,web.x,web.y,web.z,web.w};
  float at8[8] = {ata.x,ata.y,ata.z,ata.w,atb.x,atb.y,atb.z,atb.w};
  float bo8[8] = {boa.x,boa.y,boa.z,boa.w,bob.x,bob.y,bob.z,bob.w};
  float g8[8]  = {ga.x,ga.y,ga.z,ga.w,gb.x,gb.y,gb.z,gb.w};
  float b8[8]  = {ba.x,ba.y,ba.z,ba.w,bb.x,bb.y,bb.z,bb.w};
  f16x8 weh, ath;
  #pragma unroll
  for (int j = 0; j < 8; j++){ weh[j] = (_Float16)we8[j]; ath[j] = (_Float16)at8[j]; }

  int nid = blockIdx.x*4 + grp;
  if (nid >= n) return;            // per-group; no barriers below

  f16x8 xrh = *(const f16x8*)(xr + (size_t)nid*128 + c0);
  int rs = rowptr[nid], re = rowptr[nid + 1];
  float m = -3e38f, d = 0.f;
  float acc[8] = {};
  for (int e0 = rs; e0 < re; e0 += 2){
    int e1 = e0 + 1;
    bool has1 = e1 < re;
    int s0 = csr_src[e0];
    int s1 = has1 ? csr_src[e1] : s0;
    float w0 = csr_w[e0];
    float w1 = has1 ? csr_w[e1] : 0.f;
    f16x8 hv0 = *(const f16x8*)(xl + (size_t)s0*128 + c0);
    f16x8 hv1 = *(const f16x8*)(xl + (size_t)s1*128 + c0);
    float p0 = alpha8(hv0, xrh, (_Float16)w0, weh, ath);
    float p1 = alpha8(hv1, xrh, (_Float16)w1, weh, ath);
    #pragma unroll
    for (int o = 1; o < 16; o <<= 1){
      p0 += __shfl_xor(p0, o, 64);
      p1 += __shfl_xor(p1, o, 64);
    }
    if (!has1) p1 = -3e38f;
    float pm = fmaxf(p0, p1);
    if (pm > m + RT){
      float sc = __expf(m - pm);
      d *= sc;
      #pragma unroll
      for (int j = 0; j < 8; j++) acc[j] *= sc;
      m = pm;
    }
    float e0x = __expf(p0 - m), e1x = __expf(p1 - m);
    d += e0x + e1x;
    float v0[8], v1[8];
    #pragma unroll
    for (int j = 0; j < 8; j++){ v0[j] = (float)hv0[j]; v1[j] = (float)hv1[j]; }
    #pragma unroll
    for (int j = 0; j < 8; j++) acc[j] += e0x*v0[j] + e1x*v1[j];
  }
  float inv = 1.f / (d + 1e-16f);
  float o8[8];
  #pragma unroll
  for (int j = 0; j < 8; j++) o8[j] = acc[j]*inv + bo8[j];

  // LayerNorm over 128 channels (group-local)
  float s1 = 0.f, s2 = 0.f;
  #pragma unroll
  for (int j = 0; j < 8; j++){ s1 += o8[j]; s2 += o8[j]*o8[j]; }
  #pragma unroll
  for (int o = 1; o < 16; o <<= 1){ s1 += __shfl_xor(s1, o, 64); s2 += __shfl_xor(s2, o, 64); }
  float mu = s1 / 128.f;
  float var = s2 / 128.f - mu*mu;
  float rstd = rsqrtf(var + 1e-5f);
  float y[8];
  #pragma unroll
  for (int j = 0; j < 8; j++) y[j] = (o8[j] - mu)*rstd*g8[j] + b8[j];
  float* orow = out + (size_t)nid*128 + c0;
  *(float4*)orow       = make_float4(y[0],y[1],y[2],y[3]);
  *(float4*)(orow + 4) = make_float4(y[4],y[5],y[6],y[7]);
}

// ---------------- policy/value heads on one node ----------------
__global__ __launch_bounds__(128) void k_heads(const float* __restrict__ h3, const int* __restrict__ idxp,
        const float* __restrict__ Pw1, const float* __restrict__ Pb1,
        const float* __restrict__ Pw2, const float* __restrict__ Pb2,
        const float* __restrict__ Vw1, const float* __restrict__ Vb1,
        const float* __restrict__ Vw2, const float* __restrict__ Vb2,
        float* __restrict__ out){
  __shared__ float z[128], hp[128], hv[128];
  int t = threadIdx.x;
  int idx = *idxp;
  z[t] = h3[(size_t)idx*128 + t];
  __syncthreads();
  float sp = Pb1[t], sv = Vb1[t];
  for (int c = 0; c < 128; c++){
    float zc = z[c];
    sp += Pw1[t*128 + c] * zc;
    sv += Vw1[t*128 + c] * zc;
  }
  hp[t] = fmaxf(sp, 0.f);
  hv[t] = fmaxf(sv, 0.f);
  __syncthreads();
  if (t < 64){
    float l0 = Pw2[t]*hp[t]       + Pw2[64 + t]*hp[64 + t];
    float l1 = Pw2[128 + t]*hp[t] + Pw2[192 + t]*hp[64 + t];
    float vv = Vw2[t]*hv[t]       + Vw2[64 + t]*hv[64 + t];
    #pragma unroll
    for (int o = 1; o < 64; o <<= 1){
      l0 += __shfl_xor(l0, o, 64); l1 += __shfl_xor(l1, o, 64); vv += __shfl_xor(vv, o, 64);
    }
    if (t == 0){ out[0] = l0 + Pb2[0]; out[1] = l1 + Pb2[1]; out[2] = vv + Vb2[0]; }
  }
}

extern "C" void kernel_launch(void* const* d_in, const int* in_sizes, int n_in,
                              void* d_out, int out_size, void* d_ws, size_t ws_size,
                              hipStream_t stream){
  const float* x    = (const float*)d_in[0];
  const int*   ei   = (const int*)d_in[1];
  const float* ew   = (const float*)d_in[2];
  const int*   nidx = (const int*)d_in[3];
  const float* Wl1 = (const float*)d_in[4];  const float* bl1 = (const float*)d_in[5];
  const float* Wr1 = (const float*)d_in[6];  const float* br1 = (const float*)d_in[7];
  const float* We1 = (const float*)d_in[8];  const float* att1 = (const float*)d_in[9];
  const float* bo1 = (const float*)d_in[10];
  const float* Wl2 = (const float*)d_in[11]; const float* bl2 = (const float*)d_in[12];
  const float* Wr2 = (const float*)d_in[13]; const float* br2 = (const float*)d_in[14];
  const float* We2 = (const float*)d_in[15]; const float* att2 = (const float*)d_in[16];
  const float* bo2 = (const float*)d_in[17];
  const float* Wl3 = (const float*)d_in[18]; const float* bl3 = (const float*)d_in[19];
  const float* Wr3 = (const float*)d_in[20]; const float* br3 = (const float*)d_in[21];
  const float* We3 = (const float*)d_in[22]; const float* att3 = (const float*)d_in[23];
  const float* bo3 = (const float*)d_in[24];
  const float* gn1 = (const float*)d_in[25]; const float* bn1 = (const float*)d_in[26];
  const float* gn2 = (const float*)d_in[27]; const float* bn2 = (const float*)d_in[28];
  const float* gn3 = (const float*)d_in[29]; const float* bn3 = (const float*)d_in[30];
  const float* Pw1 = (const float*)d_in[31]; const float* Pb1 = (const float*)d_in[32];
  const float* Pw2 = (const float*)d_in[33]; const float* Pb2 = (const float*)d_in[34];
  const float* Vw1 = (const float*)d_in[35]; const float* Vb1 = (const float*)d_in[36];
  const float* Vw2 = (const float*)d_in[37]; const float* Vb2 = (const float*)d_in[38];

  const int N = in_sizes[0] / 16;
  const int E = in_sizes[2];
  const int NE = N + E;

  char* w = (char*)d_ws;
  size_t off = 0;
  float* sum_ew = (float*)(w + off); off += 256;
  int* rowptr = (int*)(w + off); off += (size_t)(N + 1)*4; off = (off + 255) & ~(size_t)255;
  int* cursor = (int*)(w + off); off += (size_t)N*4;       off = (off + 255) & ~(size_t)255;
  int* deg    = (int*)(w + off); off += (size_t)N*4;       off = (off + 255) & ~(size_t)255;
  int* csr_src= (int*)(w + off); off += (size_t)NE*4;      off = (off + 255) & ~(size_t)255;
  float* csr_w= (float*)(w + off); off += (size_t)NE*4;    off = (off + 255) & ~(size_t)255;
  // weight bf16 planes (single hi plane each)
  u16* W2lh = (u16*)(w + off); off += (size_t)512*512*2;
  u16* W2rh = (u16*)(w + off); off += (size_t)512*512*2;
  u16* W3lh = (u16*)(w + off); off += (size_t)128*512*2;
  u16* W3rh = (u16*)(w + off); off += (size_t)128*512*2;
  off = (off + 1048575) & ~(size_t)1048575;   // 1MB align for big buffers
  _Float16* A  = (_Float16*)(w + off); off += (size_t)N*512*2;
  _Float16* B  = (_Float16*)(w + off); off += (size_t)N*512*2;
  u16*   Ch = (u16*)(w + off);   off += (size_t)N*512*2;
  u16*   Cl = (u16*)(w + off);   off += (size_t)N*512*2;
  float* D  = (float*)(w + off); off += (size_t)N*128*4;
  (void)ws_size; (void)n_in; (void)out_size;

  hipMemsetAsync(sum_ew, 0, 4, stream);
  hipMemsetAsync(deg, 0, (size_t)N*4, stream);

  k_prep<<<256, 256, 0, stream>>>(ei + E, ew, E, deg, sum_ew);
  k_scan<<<1, 1024, 0, stream>>>(deg, rowptr, cursor, N);
  k_scatter<<<(NE + 255)/256, 256, 0, stream>>>(ei, ew, E, N, sum_ew, cursor, csr_src, csr_w);
  k_splitW<<<2560, 256, 0, stream>>>(Wl2, Wr2, Wl3, Wr3, W2lh, W2rh, W3lh, W3rh);

  const int GY = (N + 127)/128;

  // Layer 1
  k_lin1<<<N/32, 256, 0, stream>>>(x, Wl1, bl1, Wr1, br1, A, B, N);
  k_agg4<<<(N + 3)/4, 256, 0, stream>>>(A, B, We1, att1, bo1, gn1, bn1,
                                        rowptr, csr_src, csr_w, Ch, Cl, N);
  // Layer 2 (fused Wl+Wr dispatch)
  k_gemm_mfma<<<dim3(8, GY), 256, 0, stream>>>(Ch, Cl, W2lh, W2rh, bl2, br2, A, B, N, 512, 512);
  k_agg4<<<(N + 3)/4, 256, 0, stream>>>(A, B, We2, att2, bo2, gn2, bn2,
                                        rowptr, csr_src, csr_w, Ch, Cl, N);
  // Layer 3 (fused)
  k_gemm_mfma<<<dim3(2, GY), 256, 0, stream>>>(Ch, Cl, W3lh, W3rh, bl3, br3, A, B, N, 512, 128);
  k_agg1<<<(N + 3)/4, 64, 0, stream>>>(A, B, We3, att3, bo3, gn3, bn3,
                                       rowptr, csr_src, csr_w, D, N);
  // Heads
  k_heads<<<1, 128, 0, stream>>>(D, nidx, Pw1, Pb1, Pw2, Pb2, Vw1, Vb1, Vw2, Vb2, (float*)d_out);
}

// Round 11
// 535.772 us; speedup vs baseline: 1.4690x; 1.1935x over previous
//
#include <hip/hip_runtime.h>
#include <math.h>

#define NEG_SLOPE 0.2f

typedef unsigned short u16;
typedef unsigned int u32;
typedef __attribute__((ext_vector_type(8))) short bf16x8;
typedef __attribute__((ext_vector_type(8))) _Float16 f16x8;
typedef __attribute__((ext_vector_type(2))) _Float16 f16x2;
typedef __attribute__((ext_vector_type(4))) float f32x4;

__device__ __forceinline__ float wave_sum(float v){
  #pragma unroll
  for (int o = 1; o < 64; o <<= 1) v += __shfl_xor(v, o, 64);
  return v;
}

__device__ __forceinline__ u16 f2bf(float f){
  u32 u = __float_as_uint(f);
  return (u16)((u + 0x7FFF + ((u >> 16) & 1)) >> 16);
}
__device__ __forceinline__ float bf2f(u16 h){
  return __uint_as_float(((u32)h) << 16);
}

__device__ __forceinline__ void gl_lds16(const void* g, void* l){
  __builtin_amdgcn_global_load_lds((const __attribute__((address_space(1))) u32*)g,
                                   (__attribute__((address_space(3))) u32*)l, 16, 0, 0);
}

// alpha contribution of 8 channels: dot(leaky(v + xr + w*we), att) in packed f16
__device__ __forceinline__ float alpha8(f16x8 hv, f16x8 xrh, _Float16 wh, f16x8 weh, f16x8 ath){
  f16x8 tv = hv + xrh + weh*wh;
  f16x8 zero = {0,0,0,0,0,0,0,0};
  f16x8 pos = __builtin_elementwise_max(tv, zero);
  f16x8 neg = __builtin_elementwise_min(tv, zero);
  f16x8 lk  = pos + neg*(_Float16)NEG_SLOPE;
  float p = 0.f;
#if __has_builtin(__builtin_amdgcn_fdot2)
  #pragma unroll
  for (int i = 0; i < 4; i++){
    f16x2 a = {lk[2*i], lk[2*i+1]};
    f16x2 b = {ath[2*i], ath[2*i+1]};
    p = __builtin_amdgcn_fdot2(a, b, p, false);
  }
#else
  #pragma unroll
  for (int j = 0; j < 8; j++) p += (float)lk[j]*(float)ath[j];
#endif
  return p;
}

// ---------------- fused: degree histogram (dst) + edge-weight sum ----------------
__global__ void k_prep(const int* __restrict__ dst, const float* __restrict__ ew, int E,
                       int* __restrict__ deg, float* __restrict__ sum_ew){
  float s = 0.f;
  for (int i = blockIdx.x*blockDim.x + threadIdx.x; i < E; i += gridDim.x*blockDim.x){
    atomicAdd(&deg[dst[i]], 1);
    s += ew[i];
  }
  s = wave_sum(s);
  __shared__ float red[4];
  int lane = threadIdx.x & 63, wid = threadIdx.x >> 6;
  if (lane == 0) red[wid] = s;
  __syncthreads();
  if (threadIdx.x == 0){
    float t = 0.f;
    for (int i = 0; i < (int)(blockDim.x >> 6); i++) t += red[i];
    atomicAdd(sum_ew, t);
  }
}

// ---------------- exclusive scan over N nodes (deg+1 each: self loops) ----------------
__global__ __launch_bounds__(1024) void k_scan(const int* __restrict__ deg, int* __restrict__ rowptr,
                                               int* __restrict__ cursor, int n){
  __shared__ int sums[1024];
  int t = threadIdx.x;
  int CH = (n + 1023) >> 10;
  int base = t*CH;
  int local = 0;
  for (int i = 0; i < CH; i++){ int idx = base + i; if (idx < n) local += deg[idx] + 1; }
  sums[t] = local;
  __syncthreads();
  for (int off = 1; off < 1024; off <<= 1){
    int v = (t >= off) ? sums[t-off] : 0;
    __syncthreads();
    sums[t] += v;
    __syncthreads();
  }
  int run = sums[t] - local;   // exclusive prefix
  for (int i = 0; i < CH; i++){
    int idx = base + i;
    if (idx < n){ rowptr[idx] = run; cursor[idx] = run; run += deg[idx] + 1; }
  }
  if (t == 0) rowptr[n] = sums[1023];
}

// ---------------- scatter edges (+ self loops) into CSR ----------------
__global__ void k_scatter(const int* __restrict__ ei, const float* __restrict__ ew, int E, int n,
                          const float* __restrict__ sum_ew, int* __restrict__ cursor,
                          int* __restrict__ csr_src, float* __restrict__ csr_w){
  int i = blockIdx.x*blockDim.x + threadIdx.x;
  if (i >= E + n) return;
  if (i < E){
    int s = ei[i];         // row 0 = src
    int d = ei[E + i];     // row 1 = dst
    int pos = atomicAdd(&cursor[d], 1);
    csr_src[pos] = s; csr_w[pos] = ew[i];
  } else {
    int v = i - E;
    int pos = atomicAdd(&cursor[v], 1);
    csr_src[pos] = v; csr_w[pos] = (*sum_ew) / (float)E;
  }
}

// ---------------- all 4 weight planes f32->bf16 in one kernel ----------------
__global__ void k_splitW(const float* __restrict__ Wl2, const float* __restrict__ Wr2,
                         const float* __restrict__ Wl3, const float* __restrict__ Wr3,
                         u16* __restrict__ W2lh, u16* __restrict__ W2rh,
                         u16* __restrict__ W3lh, u16* __restrict__ W3rh){
  int i = blockIdx.x*blockDim.x + threadIdx.x;       // grid covers 655360
  if (i < 262144)      W2lh[i]          = f2bf(Wl2[i]);
  else if (i < 524288) W2rh[i - 262144] = f2bf(Wr2[i - 262144]);
  else if (i < 589824) W3lh[i - 524288] = f2bf(Wl3[i - 524288]);
  else if (i < 655360) W3rh[i - 589824] = f2bf(Wr3[i - 589824]);
}

// ---------------- layer-1 linear: x(Nx16) -> xl,xr (Nx512) f16 ----------------
__global__ __launch_bounds__(256) void k_lin1(const float* __restrict__ x,
        const float* __restrict__ Wl, const float* __restrict__ bl,
        const float* __restrict__ Wr, const float* __restrict__ br,
        _Float16* __restrict__ xl, _Float16* __restrict__ xr, int n){
  __shared__ float Ws[16][1028];   // transposed, padded
  __shared__ float bs[1024];
  __shared__ float xs[32][16];
  int t = threadIdx.x;
  for (int i = t; i < 512*16; i += 256){
    int j = i >> 4, k = i & 15;
    Ws[k][j] = Wl[i];
    Ws[k][512 + j] = Wr[i];
  }
  for (int i = t; i < 512; i += 256){ bs[i] = bl[i]; bs[512 + i] = br[i]; }
  int n0 = blockIdx.x * 32;
  for (int i = t; i < 32*16; i += 256){ int r = i >> 4, k = i & 15; xs[r][k] = x[(size_t)(n0 + r)*16 + k]; }
  __syncthreads();
  for (int idx = t; idx < 32*1024; idx += 256){
    int r = idx >> 10, c = idx & 1023;
    float s = bs[c];
    #pragma unroll
    for (int k = 0; k < 16; k++) s += xs[r][k] * Ws[k][c];
    int nn = n0 + r;
    if (c < 512) xl[(size_t)nn*512 + c] = (_Float16)s;
    else         xr[(size_t)nn*512 + (c - 512)] = (_Float16)s;
  }
}

// ---------------- split-A-bf16 x bf16-W MFMA GEMM (2 MFMA terms), fused Wl+Wr ----------------
__global__ __launch_bounds__(256,4) void k_gemm_mfma(
    const u16* __restrict__ Ah, const u16* __restrict__ Al,
    const u16* __restrict__ Wlh, const u16* __restrict__ Wrh,
    const float* __restrict__ biasl, const float* __restrict__ biasr,
    _Float16* __restrict__ outl, _Float16* __restrict__ outr,
    int n, int K, int J){
  __shared__ __align__(16) u16 lds[12288];   // 24KB: Ah,Al,W planes of 4096 u16
  u16* lA_h = lds;
  u16* lA_l = lds + 4096;
  u16* lW   = lds + 8192;
  int t = threadIdx.x;
  int lane = t & 63, w = t >> 6;
  int lane15 = lane & 15, lgrp = lane >> 4;
  int jb = J >> 7;
  int side = blockIdx.x / jb;
  int j0 = (blockIdx.x - side*jb) * 128;
  const u16* Wh = side ? Wrh : Wlh;
  const float* bias = side ? biasr : biasl;
  _Float16* out = side ? outr : outl;
  int n0 = blockIdx.y * 128;
  int wm = (w >> 1) * 64, wn = (w & 1) * 64;
  f32x4 acc[4][4] = {};

  int s0 = t, s1 = t + 256;
  int r0 = s0 >> 2, r1 = s1 >> 2;
  int sl0 = (s0 & 3) ^ ((r0 >> 1) & 3);
  int sl1 = (s1 & 3) ^ ((r1 >> 1) & 3);
  size_t arow0 = (size_t)min(n0 + r0, n - 1) * K + sl0*8;
  size_t arow1 = (size_t)min(n0 + r1, n - 1) * K + sl1*8;
  size_t wrow0 = (size_t)(j0 + r0) * K + sl0*8;
  size_t wrow1 = (size_t)(j0 + r1) * K + sl1*8;

  int rcol = (lgrp * 16) ^ (((lane15 >> 1) & 3) << 4);

  for (int k0 = 0; k0 < K; k0 += 32){
    gl_lds16(Ah + arow0 + k0, lA_h + s0*8);
    gl_lds16(Ah + arow1 + k0, lA_h + s1*8);
    gl_lds16(Al + arow0 + k0, lA_l + s0*8);
    gl_lds16(Al + arow1 + k0, lA_l + s1*8);
    gl_lds16(Wh + wrow0 + k0, lW + s0*8);
    gl_lds16(Wh + wrow1 + k0, lW + s1*8);
    __syncthreads();
    bf16x8 ah[4], al[4], bh[4];
    #pragma unroll
    for (int i = 0; i < 4; i++){
      int qa = (wm + i*16 + lane15)*64 + rcol;
      ah[i]  = *(const bf16x8*)((const char*)lA_h + qa);
      al[i]  = *(const bf16x8*)((const char*)lA_l + qa);
      int qb = (wn + i*16 + lane15)*64 + rcol;
      bh[i]  = *(const bf16x8*)((const char*)lW + qb);
    }
    #pragma unroll
    for (int mi = 0; mi < 4; mi++)
      #pragma unroll
      for (int ni = 0; ni < 4; ni++){
        acc[mi][ni] = __builtin_amdgcn_mfma_f32_16x16x32_bf16(al[mi], bh[ni], acc[mi][ni], 0, 0, 0);
        acc[mi][ni] = __builtin_amdgcn_mfma_f32_16x16x32_bf16(ah[mi], bh[ni], acc[mi][ni], 0, 0, 0);
      }
    __syncthreads();
  }

  #pragma unroll
  for (int ni = 0; ni < 4; ni++){
    int col = j0 + wn + ni*16 + lane15;
    float bia = bias[col];
    #pragma unroll
    for (int mi = 0; mi < 4; mi++){
      int rowb = n0 + wm + mi*16 + lgrp*4;
      #pragma unroll
      for (int rg = 0; rg < 4; rg++){
        int row = rowb + rg;
        if (row < n) out[(size_t)row*J + col] = (_Float16)(acc[mi][ni][rg] + bia);
      }
    }
  }
}

// ---------------- GATv2 4-head agg + bias + LayerNorm + ELU, emit hi/lo bf16 ----------------
// ONE WAVE per node: lane owns channels (lane>>4)*128 + (lane&15)*8, so the 4
// 16-lane groups are the 4 heads, all processing the SAME edge list in lockstep.
// No cross-group merge, LN = in-wave butterfly, zero barriers/LDS. rs/re/e0 are
// wave-uniform (readfirstlane) -> csr loads scalarize. Block = 2 independent
// waves; NB=2 nodes per wave. Defer-max THR=8; packed-f16 alpha; f32 softmax.
__global__ __launch_bounds__(128) void k_agg4(
                      const _Float16* __restrict__ xl, const _Float16* __restrict__ xr,
                      const float* __restrict__ We, const float* __restrict__ att, const float* __restrict__ bo,
                      const float* __restrict__ gam, const float* __restrict__ bet,
                      const int* __restrict__ rowptr, const int* __restrict__ csr_src,
                      const float* __restrict__ csr_w,
                      u16* __restrict__ oh, u16* __restrict__ ol, int n){
  constexpr int HC_ = 512;
  constexpr float RT = 8.f;
  constexpr int NB = 2;
  int t = threadIdx.x;
  int widx = t >> 6, lane = t & 63;
  int l16 = lane & 15, grp = lane >> 4;    // grp = head
  int c0 = grp*128 + l16*8;                // 8 channels per lane, unique per lane

  // edge-phase params in f16 only (keeps loop VGPRs low)
  float4 wea = *(const float4*)&We[c0],  web = *(const float4*)&We[c0 + 4];
  float4 ata = *(const float4*)&att[c0], atb = *(const float4*)&att[c0 + 4];
  f16x8 weh, ath;
  #pragma unroll
  for (int j = 0; j < 4; j++){
    weh[j] = (_Float16)((&wea.x)[j]); weh[4+j] = (_Float16)((&web.x)[j]);
    ath[j] = (_Float16)((&ata.x)[j]); ath[4+j] = (_Float16)((&atb.x)[j]);
  }

  #pragma unroll 1
  for (int ib = 0; ib < NB; ib++){
    int nid = blockIdx.x*(2*NB) + widx*NB + ib;
    if (nid >= n) continue;                // wave-uniform; no barriers anywhere

    f16x8 xrh = *(const f16x8*)(xr + (size_t)nid*HC_ + c0);
    int rs = __builtin_amdgcn_readfirstlane(rowptr[nid]);
    int re = __builtin_amdgcn_readfirstlane(rowptr[nid + 1]);

    float m = -3e38f, d = 0.f;
    float acc[8] = {};
    for (int e0 = rs; e0 < re; e0 += 2){
      int e1 = e0 + 1;
      bool has1 = e1 < re;
      int s0 = csr_src[e0];
      int s1 = has1 ? csr_src[e1] : s0;
      float w0 = csr_w[e0];
      float w1 = has1 ? csr_w[e1] : 0.f;
      f16x8 hv0 = *(const f16x8*)(xl + (size_t)s0*HC_ + c0);
      f16x8 hv1 = *(const f16x8*)(xl + (size_t)s1*HC_ + c0);
      float p0 = alpha8(hv0, xrh, (_Float16)w0, weh, ath);
      float p1 = alpha8(hv1, xrh, (_Float16)w1, weh, ath);
      #pragma unroll
      for (int o = 1; o < 16; o <<= 1){    // reduce within 16-lane head group
        p0 += __shfl_xor(p0, o, 64);
        p1 += __shfl_xor(p1, o, 64);
      }
      if (!has1) p1 = -3e38f;
      float pm = fmaxf(p0, p1);
      if (pm > m + RT){                    // rare rescale (defer-max)
        float sc = __expf(m - pm);
        d *= sc;
        #pragma unroll
        for (int j = 0; j < 8; j++) acc[j] *= sc;
        m = pm;
      }
      float e0x = __expf(p0 - m), e1x = __expf(p1 - m);
      d += e0x + e1x;
      float v0[8], v1[8];
      #pragma unroll
      for (int j = 0; j < 8; j++){ v0[j] = (float)hv0[j]; v1[j] = (float)hv1[j]; }
      #pragma unroll
      for (int j = 0; j < 8; j++) acc[j] += e0x*v0[j] + e1x*v1[j];
    }
    // each head group processed ALL edges -> no cross-group merge needed
    float inv = 1.f / (d + 1e-16f);
    float4 boa = *(const float4*)&bo[c0], bob = *(const float4*)&bo[c0 + 4];
    float o8[8];
    #pragma unroll
    for (int j = 0; j < 4; j++){
      o8[j]   = acc[j]*inv   + (&boa.x)[j];
      o8[4+j] = acc[4+j]*inv + (&bob.x)[j];
    }

    // LayerNorm over all 512 channels: in-wave 6-step butterfly
    float s1 = 0.f, s2 = 0.f;
    #pragma unroll
    for (int j = 0; j < 8; j++){ s1 += o8[j]; s2 += o8[j]*o8[j]; }
    #pragma unroll
    for (int o = 1; o < 64; o <<= 1){ s1 += __shfl_xor(s1, o, 64); s2 += __shfl_xor(s2, o, 64); }
    float mu = s1 / (float)HC_;
    float var = s2 / (float)HC_ - mu*mu;
    float rstd = rsqrtf(var + 1e-5f);
    float4 ga = *(const float4*)&gam[c0], gb = *(const float4*)&gam[c0 + 4];
    float4 ba = *(const float4*)&bet[c0], bb = *(const float4*)&bet[c0 + 4];
    float y[8];
    #pragma unroll
    for (int j = 0; j < 4; j++){
      float ya = (o8[j]   - mu)*rstd*(&ga.x)[j] + (&ba.x)[j];
      float yb = (o8[4+j] - mu)*rstd*(&gb.x)[j] + (&bb.x)[j];
      y[j]   = (ya > 0.f) ? ya : (__expf(ya) - 1.f);   // ELU
      y[4+j] = (yb > 0.f) ? yb : (__expf(yb) - 1.f);
    }
    // every lane writes its own 8 channels: hi/lo bf16 planes, 16B each
    u32 hv2[4], lv2[4];
    #pragma unroll
    for (int j = 0; j < 4; j++){
      u16 h0 = f2bf(y[2*j]), h1 = f2bf(y[2*j+1]);
      u16 l0 = f2bf(y[2*j] - bf2f(h0)), l1 = f2bf(y[2*j+1] - bf2f(h1));
      hv2[j] = (u32)h0 | ((u32)h1 << 16);
      lv2[j] = (u32)l0 | ((u32)l1 << 16);
    }
    *(uint4*)&oh[(size_t)nid*HC_ + c0] = make_uint4(hv2[0],hv2[1],hv2[2],hv2[3]);
    *(uint4*)&ol[(size_t)nid*HC_ + c0] = make_uint4(lv2[0],lv2[1],lv2[2],lv2[3]);
  }
}

// ---------------- layer-3 agg (1 head, no ELU, f32 out): one node per 16-lane group ----------------
// 64-thread blocks; wave = 4 groups = 4 nodes. No cross-group merge; LN group-local.
__global__ __launch_bounds__(64) void k_agg1(
                      const _Float16* __restrict__ xl, const _Float16* __restrict__ xr,
                      const float* __restrict__ We, const float* __restrict__ att, const float* __restrict__ bo,
                      const float* __restrict__ gam, const float* __restrict__ bet,
                      const int* __restrict__ rowptr, const int* __restrict__ csr_src,
                      const float* __restrict__ csr_w,
                      float* __restrict__ out, int n){
  constexpr float RT = 8.f;
  int lane = threadIdx.x;
  int l16 = lane & 15, grp = lane >> 4;
  int c0 = l16*8;

  float4 wea = *(const float4*)&We[c0],  web = *(const float4*)&We[c0 + 4];
  float4 ata = *(const float4*)&att[c0], atb = *(const float4*)&att[c0 + 4];
  float4 boa = *(const float4*)&bo[c0],  bob = *(const float4*)&bo[c0 + 4];
  float4 ga  = *(const float4*)&gam[c0], gb  = *(const float4*)&gam[c0 + 4];
  float4 ba  = *(const float4*)&bet[c0], bb  = *(const float4*)&bet[c0 + 4];
  float bo8[8] = {boa.x,boa.y,boa.z,boa.w,bob.x,bob.y,bob.z,bob.w};
  float g8[8]  = {ga.x,ga.y,ga.z,ga.w,gb.x,gb.y,gb.z,gb.w};
  float b8[8]  = {ba.x,ba.y,ba.z,ba.w,bb.x,bb.y,bb.z,bb.w};
  f16x8 weh, ath;
  #pragma unroll
  for (int j = 0; j < 4; j++){
    weh[j] = (_Float16)((&wea.x)[j]); weh[4+j] = (_Float16)((&web.x)[j]);
    ath[j] = (_Float16)((&ata.x)[j]); ath[4+j] = (_Float16)((&atb.x)[j]);
  }

  int nid = blockIdx.x*4 + grp;
  if (nid >= n) return;            // per-group; no barriers below

  f16x8 xrh = *(const f16x8*)(xr + (size_t)nid*128 + c0);
  int rs = rowptr[nid], re = rowptr[nid + 1];
  float m = -3e38f, d = 0.f;
  float acc[8] = {};
  for (int e0 = rs; e0 < re; e0 += 2){
    int e1 = e0 + 1;
    bool has1 = e1 < re;
    int s0 = csr_src[e0];
    int s1 = has1 ? csr_src[e1] : s0;
    float w0 = csr_w[e0];
    float w1 = has1 ? csr_w[e1] : 0.f;
    f16x8 hv0 = *(const f16x8*)(xl + (size_t)s0*128 + c0);
    f16x8 hv1 = *(const f16x8*)(xl + (size_t)s1*128 + c0);
    float p0 = alpha8(hv0, xrh, (_Float16)w0, weh, ath);
    float p1 = alpha8(hv1, xrh, (_Float16)w1, weh, ath);
    #pragma unroll
    for (int o = 1; o < 16; o <<= 1){
      p0 += __shfl_xor(p0, o, 64);
      p1 += __shfl_xor(p1, o, 64);
    }
    if (!has1) p1 = -3e38f;
    float pm = fmaxf(p0, p1);
    if (pm > m + RT){
      float sc = __expf(m - pm);
      d *= sc;
      #pragma unroll
      for (int j = 0; j < 8; j++) acc[j] *= sc;
      m = pm;
    }
    float e0x = __expf(p0 - m), e1x = __expf(p1 - m);
    d += e0x + e1x;
    float v0[8], v1[8];
    #pragma unroll
    for (int j = 0; j < 8; j++){ v0[j] = (float)hv0[j]; v1[j] = (float)hv1[j]; }
    #pragma unroll
    for (int j = 0; j < 8; j++) acc[j] += e0x*v0[j] + e1x*v1[j];
  }
  float inv = 1.f / (d + 1e-16f);
  float o8[8];
  #pragma unroll
  for (int j = 0; j < 8; j++) o8[j] = acc[j]*inv + bo8[j];

  // LayerNorm over 128 channels (group-local)
  float s1 = 0.f, s2 = 0.f;
  #pragma unroll
  for (int j = 0; j < 8; j++){ s1 += o8[j]; s2 += o8[j]*o8[j]; }
  #pragma unroll
  for (int o = 1; o < 16; o <<= 1){ s1 += __shfl_xor(s1, o, 64); s2 += __shfl_xor(s2, o, 64); }
  float mu = s1 / 128.f;
  float var = s2 / 128.f - mu*mu;
  float rstd = rsqrtf(var + 1e-5f);
  float y[8];
  #pragma unroll
  for (int j = 0; j < 8; j++) y[j] = (o8[j] - mu)*rstd*g8[j] + b8[j];
  float* orow = out + (size_t)nid*128 + c0;
  *(float4*)orow       = make_float4(y[0],y[1],y[2],y[3]);
  *(float4*)(orow + 4) = make_float4(y[4],y[5],y[6],y[7]);
}

// ---------------- policy/value heads on one node ----------------
__global__ __launch_bounds__(128) void k_heads(const float* __restrict__ h3, const int* __restrict__ idxp,
        const float* __restrict__ Pw1, const float* __restrict__ Pb1,
        const float* __restrict__ Pw2, const float* __restrict__ Pb2,
        const float* __restrict__ Vw1, const float* __restrict__ Vb1,
        const float* __restrict__ Vw2, const float* __restrict__ Vb2,
        float* __restrict__ out){
  __shared__ float z[128], hp[128], hv[128];
  int t = threadIdx.x;
  int idx = *idxp;
  z[t] = h3[(size_t)idx*128 + t];
  __syncthreads();
  float sp = Pb1[t], sv = Vb1[t];
  for (int c = 0; c < 128; c++){
    float zc = z[c];
    sp += Pw1[t*128 + c] * zc;
    sv += Vw1[t*128 + c] * zc;
  }
  hp[t] = fmaxf(sp, 0.f);
  hv[t] = fmaxf(sv, 0.f);
  __syncthreads();
  if (t < 64){
    float l0 = Pw2[t]*hp[t]       + Pw2[64 + t]*hp[64 + t];
    float l1 = Pw2[128 + t]*hp[t] + Pw2[192 + t]*hp[64 + t];
    float vv = Vw2[t]*hv[t]       + Vw2[64 + t]*hv[64 + t];
    #pragma unroll
    for (int o = 1; o < 64; o <<= 1){
      l0 += __shfl_xor(l0, o, 64); l1 += __shfl_xor(l1, o, 64); vv += __shfl_xor(vv, o, 64);
    }
    if (t == 0){ out[0] = l0 + Pb2[0]; out[1] = l1 + Pb2[1]; out[2] = vv + Vb2[0]; }
  }
}

extern "C" void kernel_launch(void* const* d_in, const int* in_sizes, int n_in,
                              void* d_out, int out_size, void* d_ws, size_t ws_size,
                              hipStream_t stream){
  const float* x    = (const float*)d_in[0];
  const int*   ei   = (const int*)d_in[1];
  const float* ew   = (const float*)d_in[2];
  const int*   nidx = (const int*)d_in[3];
  const float* Wl1 = (const float*)d_in[4];  const float* bl1 = (const float*)d_in[5];
  const float* Wr1 = (const float*)d_in[6];  const float* br1 = (const float*)d_in[7];
  const float* We1 = (const float*)d_in[8];  const float* att1 = (const float*)d_in[9];
  const float* bo1 = (const float*)d_in[10];
  const float* Wl2 = (const float*)d_in[11]; const float* bl2 = (const float*)d_in[12];
  const float* Wr2 = (const float*)d_in[13]; const float* br2 = (const float*)d_in[14];
  const float* We2 = (const float*)d_in[15]; const float* att2 = (const float*)d_in[16];
  const float* bo2 = (const float*)d_in[17];
  const float* Wl3 = (const float*)d_in[18]; const float* bl3 = (const float*)d_in[19];
  const float* Wr3 = (const float*)d_in[20]; const float* br3 = (const float*)d_in[21];
  const float* We3 = (const float*)d_in[22]; const float* att3 = (const float*)d_in[23];
  const float* bo3 = (const float*)d_in[24];
  const float* gn1 = (const float*)d_in[25]; const float* bn1 = (const float*)d_in[26];
  const float* gn2 = (const float*)d_in[27]; const float* bn2 = (const float*)d_in[28];
  const float* gn3 = (const float*)d_in[29]; const float* bn3 = (const float*)d_in[30];
  const float* Pw1 = (const float*)d_in[31]; const float* Pb1 = (const float*)d_in[32];
  const float* Pw2 = (const float*)d_in[33]; const float* Pb2 = (const float*)d_in[34];
  const float* Vw1 = (const float*)d_in[35]; const float* Vb1 = (const float*)d_in[36];
  const float* Vw2 = (const float*)d_in[37]; const float* Vb2 = (const float*)d_in[38];

  const int N = in_sizes[0] / 16;
  const int E = in_sizes[2];
  const int NE = N + E;

  char* w = (char*)d_ws;
  size_t off = 0;
  float* sum_ew = (float*)(w + off); off += 256;
  int* rowptr = (int*)(w + off); off += (size_t)(N + 1)*4; off = (off + 255) & ~(size_t)255;
  int* cursor = (int*)(w + off); off += (size_t)N*4;       off = (off + 255) & ~(size_t)255;
  int* deg    = (int*)(w + off); off += (size_t)N*4;       off = (off + 255) & ~(size_t)255;
  int* csr_src= (int*)(w + off); off += (size_t)NE*4;      off = (off + 255) & ~(size_t)255;
  float* csr_w= (float*)(w + off); off += (size_t)NE*4;    off = (off + 255) & ~(size_t)255;
  // weight bf16 planes (single hi plane each)
  u16* W2lh = (u16*)(w + off); off += (size_t)512*512*2;
  u16* W2rh = (u16*)(w + off); off += (size_t)512*512*2;
  u16* W3lh = (u16*)(w + off); off += (size_t)128*512*2;
  u16* W3rh = (u16*)(w + off); off += (size_t)128*512*2;
  off = (off + 1048575) & ~(size_t)1048575;   // 1MB align for big buffers
  _Float16* A  = (_Float16*)(w + off); off += (size_t)N*512*2;
  _Float16* B  = (_Float16*)(w + off); off += (size_t)N*512*2;
  u16*   Ch = (u16*)(w + off);   off += (size_t)N*512*2;
  u16*   Cl = (u16*)(w + off);   off += (size_t)N*512*2;
  float* D  = (float*)(w + off); off += (size_t)N*128*4;
  (void)ws_size; (void)n_in; (void)out_size;

  hipMemsetAsync(sum_ew, 0, 4, stream);
  hipMemsetAsync(deg, 0, (size_t)N*4, stream);

  k_prep<<<256, 256, 0, stream>>>(ei + E, ew, E, deg, sum_ew);
  k_scan<<<1, 1024, 0, stream>>>(deg, rowptr, cursor, N);
  k_scatter<<<(NE + 255)/256, 256, 0, stream>>>(ei, ew, E, N, sum_ew, cursor, csr_src, csr_w);
  k_splitW<<<2560, 256, 0, stream>>>(Wl2, Wr2, Wl3, Wr3, W2lh, W2rh, W3lh, W3rh);

  const int GY = (N + 127)/128;

  // Layer 1
  k_lin1<<<N/32, 256, 0, stream>>>(x, Wl1, bl1, Wr1, br1, A, B, N);
  k_agg4<<<(N + 3)/4, 128, 0, stream>>>(A, B, We1, att1, bo1, gn1, bn1,
                                        rowptr, csr_src, csr_w, Ch, Cl, N);
  // Layer 2 (fused Wl+Wr dispatch)
  k_gemm_mfma<<<dim3(8, GY), 256, 0, stream>>>(Ch, Cl, W2lh, W2rh, bl2, br2, A, B, N, 512, 512);
  k_agg4<<<(N + 3)/4, 128, 0, stream>>>(A, B, We2, att2, bo2, gn2, bn2,
                                        rowptr, csr_src, csr_w, Ch, Cl, N);
  // Layer 3 (fused)
  k_gemm_mfma<<<dim3(2, GY), 256, 0, stream>>>(Ch, Cl, W3lh, W3rh, bl3, br3, A, B, N, 512, 128);
  k_agg1<<<(N + 3)/4, 64, 0, stream>>>(A, B, We3, att3, bo3, gn3, bn3,
                                       rowptr, csr_src, csr_w, D, N);
  // Heads
  k_heads<<<1, 128, 0, stream>>>(D, nidx, Pw1, Pb1, Pw2, Pb2, Vw1, Vb1, Vw2, Vb2, (float*)d_out);
}

// Round 12
// 515.813 us; speedup vs baseline: 1.5259x; 1.0387x over previous
//
#include <hip/hip_runtime.h>
#include <math.h>

#define NEG_SLOPE 0.2f

typedef unsigned short u16;
typedef unsigned int u32;
typedef __attribute__((ext_vector_type(8))) short bf16x8;
typedef __attribute__((ext_vector_type(8))) _Float16 f16x8;
typedef __attribute__((ext_vector_type(2))) _Float16 f16x2;
typedef __attribute__((ext_vector_type(4))) float f32x4;

__device__ __forceinline__ float wave_sum(float v){
  #pragma unroll
  for (int o = 1; o < 64; o <<= 1) v += __shfl_xor(v, o, 64);
  return v;
}

__device__ __forceinline__ u16 f2bf(float f){
  u32 u = __float_as_uint(f);
  return (u16)((u + 0x7FFF + ((u >> 16) & 1)) >> 16);
}
__device__ __forceinline__ float bf2f(u16 h){
  return __uint_as_float(((u32)h) << 16);
}

__device__ __forceinline__ void gl_lds16(const void* g, void* l){
  __builtin_amdgcn_global_load_lds((const __attribute__((address_space(1))) u32*)g,
                                   (__attribute__((address_space(3))) u32*)l, 16, 0, 0);
}

// bijective XCD-chunked swizzle (m204): XCD k = lin%8 gets a contiguous chunk
// of virtual block ids -> L2 locality for blocks sharing operand panels.
__device__ __forceinline__ int xcd_swz(int lin, int nwg){
  int xcd = lin & 7;
  int q = nwg >> 3, r = nwg & 7;
  int base = (xcd < r) ? xcd*(q + 1) : r*(q + 1) + (xcd - r)*q;
  return base + (lin >> 3);
}

// alpha contribution of 8 channels: dot(leaky(v + xr + w*we), att) in packed f16
__device__ __forceinline__ float alpha8(f16x8 hv, f16x8 xrh, _Float16 wh, f16x8 weh, f16x8 ath){
  f16x8 tv = hv + xrh + weh*wh;
  f16x8 zero = {0,0,0,0,0,0,0,0};
  f16x8 pos = __builtin_elementwise_max(tv, zero);
  f16x8 neg = __builtin_elementwise_min(tv, zero);
  f16x8 lk  = pos + neg*(_Float16)NEG_SLOPE;
  float p = 0.f;
#if __has_builtin(__builtin_amdgcn_fdot2)
  #pragma unroll
  for (int i = 0; i < 4; i++){
    f16x2 a = {lk[2*i], lk[2*i+1]};
    f16x2 b = {ath[2*i], ath[2*i+1]};
    p = __builtin_amdgcn_fdot2(a, b, p, false);
  }
#else
  #pragma unroll
  for (int j = 0; j < 8; j++) p += (float)lk[j]*(float)ath[j];
#endif
  return p;
}

// ---------------- fused: degree histogram (dst) + edge-weight sum ----------------
__global__ void k_prep(const int* __restrict__ dst, const float* __restrict__ ew, int E,
                       int* __restrict__ deg, float* __restrict__ sum_ew){
  float s = 0.f;
  for (int i = blockIdx.x*blockDim.x + threadIdx.x; i < E; i += gridDim.x*blockDim.x){
    atomicAdd(&deg[dst[i]], 1);
    s += ew[i];
  }
  s = wave_sum(s);
  __shared__ float red[4];
  int lane = threadIdx.x & 63, wid = threadIdx.x >> 6;
  if (lane == 0) red[wid] = s;
  __syncthreads();
  if (threadIdx.x == 0){
    float t = 0.f;
    for (int i = 0; i < (int)(blockDim.x >> 6); i++) t += red[i];
    atomicAdd(sum_ew, t);
  }
}

// ---------------- exclusive scan over N nodes (deg+1 each: self loops) ----------------
__global__ __launch_bounds__(1024) void k_scan(const int* __restrict__ deg, int* __restrict__ rowptr,
                                               int* __restrict__ cursor, int n){
  __shared__ int sums[1024];
  int t = threadIdx.x;
  int CH = (n + 1023) >> 10;
  int base = t*CH;
  int local = 0;
  for (int i = 0; i < CH; i++){ int idx = base + i; if (idx < n) local += deg[idx] + 1; }
  sums[t] = local;
  __syncthreads();
  for (int off = 1; off < 1024; off <<= 1){
    int v = (t >= off) ? sums[t-off] : 0;
    __syncthreads();
    sums[t] += v;
    __syncthreads();
  }
  int run = sums[t] - local;   // exclusive prefix
  for (int i = 0; i < CH; i++){
    int idx = base + i;
    if (idx < n){ rowptr[idx] = run; cursor[idx] = run; run += deg[idx] + 1; }
  }
  if (t == 0) rowptr[n] = sums[1023];
}

// ---------------- scatter edges (+ self loops) into CSR ----------------
__global__ void k_scatter(const int* __restrict__ ei, const float* __restrict__ ew, int E, int n,
                          const float* __restrict__ sum_ew, int* __restrict__ cursor,
                          int* __restrict__ csr_src, float* __restrict__ csr_w){
  int i = blockIdx.x*blockDim.x + threadIdx.x;
  if (i >= E + n) return;
  if (i < E){
    int s = ei[i];         // row 0 = src
    int d = ei[E + i];     // row 1 = dst
    int pos = atomicAdd(&cursor[d], 1);
    csr_src[pos] = s; csr_w[pos] = ew[i];
  } else {
    int v = i - E;
    int pos = atomicAdd(&cursor[v], 1);
    csr_src[pos] = v; csr_w[pos] = (*sum_ew) / (float)E;
  }
}

// ---------------- all 4 weight planes f32->bf16 in one kernel ----------------
__global__ void k_splitW(const float* __restrict__ Wl2, const float* __restrict__ Wr2,
                         const float* __restrict__ Wl3, const float* __restrict__ Wr3,
                         u16* __restrict__ W2lh, u16* __restrict__ W2rh,
                         u16* __restrict__ W3lh, u16* __restrict__ W3rh){
  int i = blockIdx.x*blockDim.x + threadIdx.x;       // grid covers 655360
  if (i < 262144)      W2lh[i]          = f2bf(Wl2[i]);
  else if (i < 524288) W2rh[i - 262144] = f2bf(Wr2[i - 262144]);
  else if (i < 589824) W3lh[i - 524288] = f2bf(Wl3[i - 524288]);
  else if (i < 655360) W3rh[i - 589824] = f2bf(Wr3[i - 589824]);
}

// ---------------- layer-1 linear: x(Nx16) -> xl,xr (Nx512) f16 ----------------
__global__ __launch_bounds__(256) void k_lin1(const float* __restrict__ x,
        const float* __restrict__ Wl, const float* __restrict__ bl,
        const float* __restrict__ Wr, const float* __restrict__ br,
        _Float16* __restrict__ xl, _Float16* __restrict__ xr, int n){
  __shared__ float Ws[16][1028];   // transposed, padded
  __shared__ float bs[1024];
  __shared__ float xs[32][16];
  int t = threadIdx.x;
  for (int i = t; i < 512*16; i += 256){
    int j = i >> 4, k = i & 15;
    Ws[k][j] = Wl[i];
    Ws[k][512 + j] = Wr[i];
  }
  for (int i = t; i < 512; i += 256){ bs[i] = bl[i]; bs[512 + i] = br[i]; }
  int n0 = blockIdx.x * 32;
  for (int i = t; i < 32*16; i += 256){ int r = i >> 4, k = i & 15; xs[r][k] = x[(size_t)(n0 + r)*16 + k]; }
  __syncthreads();
  for (int idx = t; idx < 32*1024; idx += 256){
    int r = idx >> 10, c = idx & 1023;
    float s = bs[c];
    #pragma unroll
    for (int k = 0; k < 16; k++) s += xs[r][k] * Ws[k][c];
    int nn = n0 + r;
    if (c < 512) xl[(size_t)nn*512 + c] = (_Float16)s;
    else         xr[(size_t)nn*512 + (c - 512)] = (_Float16)s;
  }
}

// ---------------- split-A-bf16 x bf16-W MFMA GEMM (2 MFMA terms), fused Wl+Wr ----------------
// XCD-chunked block swizzle: each XCD's L2 reuses the A row-panel across the 8
// column/side blocks that share it (FETCH was 4.6x unique bytes without it).
__global__ __launch_bounds__(256,4) void k_gemm_mfma(
    const u16* __restrict__ Ah, const u16* __restrict__ Al,
    const u16* __restrict__ Wlh, const u16* __restrict__ Wrh,
    const float* __restrict__ biasl, const float* __restrict__ biasr,
    _Float16* __restrict__ outl, _Float16* __restrict__ outr,
    int n, int K, int J){
  __shared__ __align__(16) u16 lds[12288];   // 24KB: Ah,Al,W planes of 4096 u16
  u16* lA_h = lds;
  u16* lA_l = lds + 4096;
  u16* lW   = lds + 8192;
  int t = threadIdx.x;
  int lane = t & 63, w = t >> 6;
  int lane15 = lane & 15, lgrp = lane >> 4;

  int nwg = gridDim.x * gridDim.y;
  int lin = blockIdx.y * gridDim.x + blockIdx.x;
  int swz = xcd_swz(lin, nwg);
  int bx = swz % gridDim.x;            // column/side block (fast within chunk)
  int by = swz / gridDim.x;            // row panel

  int jb = J >> 7;
  int side = bx / jb;
  int j0 = (bx - side*jb) * 128;
  const u16* Wh = side ? Wrh : Wlh;
  const float* bias = side ? biasr : biasl;
  _Float16* out = side ? outr : outl;
  int n0 = by * 128;
  int wm = (w >> 1) * 64, wn = (w & 1) * 64;
  f32x4 acc[4][4] = {};

  int s0 = t, s1 = t + 256;
  int r0 = s0 >> 2, r1 = s1 >> 2;
  int sl0 = (s0 & 3) ^ ((r0 >> 1) & 3);
  int sl1 = (s1 & 3) ^ ((r1 >> 1) & 3);
  size_t arow0 = (size_t)min(n0 + r0, n - 1) * K + sl0*8;
  size_t arow1 = (size_t)min(n0 + r1, n - 1) * K + sl1*8;
  size_t wrow0 = (size_t)(j0 + r0) * K + sl0*8;
  size_t wrow1 = (size_t)(j0 + r1) * K + sl1*8;

  int rcol = (lgrp * 16) ^ (((lane15 >> 1) & 3) << 4);

  for (int k0 = 0; k0 < K; k0 += 32){
    gl_lds16(Ah + arow0 + k0, lA_h + s0*8);
    gl_lds16(Ah + arow1 + k0, lA_h + s1*8);
    gl_lds16(Al + arow0 + k0, lA_l + s0*8);
    gl_lds16(Al + arow1 + k0, lA_l + s1*8);
    gl_lds16(Wh + wrow0 + k0, lW + s0*8);
    gl_lds16(Wh + wrow1 + k0, lW + s1*8);
    __syncthreads();
    bf16x8 ah[4], al[4], bh[4];
    #pragma unroll
    for (int i = 0; i < 4; i++){
      int qa = (wm + i*16 + lane15)*64 + rcol;
      ah[i]  = *(const bf16x8*)((const char*)lA_h + qa);
      al[i]  = *(const bf16x8*)((const char*)lA_l + qa);
      int qb = (wn + i*16 + lane15)*64 + rcol;
      bh[i]  = *(const bf16x8*)((const char*)lW + qb);
    }
    #pragma unroll
    for (int mi = 0; mi < 4; mi++)
      #pragma unroll
      for (int ni = 0; ni < 4; ni++){
        acc[mi][ni] = __builtin_amdgcn_mfma_f32_16x16x32_bf16(al[mi], bh[ni], acc[mi][ni], 0, 0, 0);
        acc[mi][ni] = __builtin_amdgcn_mfma_f32_16x16x32_bf16(ah[mi], bh[ni], acc[mi][ni], 0, 0, 0);
      }
    __syncthreads();
  }

  #pragma unroll
  for (int ni = 0; ni < 4; ni++){
    int col = j0 + wn + ni*16 + lane15;
    float bia = bias[col];
    #pragma unroll
    for (int mi = 0; mi < 4; mi++){
      int rowb = n0 + wm + mi*16 + lgrp*4;
      #pragma unroll
      for (int rg = 0; rg < 4; rg++){
        int row = rowb + rg;
        if (row < n) out[(size_t)row*J + col] = (_Float16)(acc[mi][ni][rg] + bia);
      }
    }
  }
}

// ---------------- GATv2 4-head agg + bias + LayerNorm + ELU, emit hi/lo bf16 ----------------
// ONE WAVE per node: lane owns channels (lane>>4)*128 + (lane&15)*8, so the 4
// 16-lane groups are the 4 heads, all processing the SAME edge list in lockstep.
// No cross-group merge, LN = in-wave butterfly, zero barriers/LDS. rs/re/e0 are
// wave-uniform (readfirstlane) -> csr loads scalarize. Block = 2 independent
// waves; NB=2 nodes per wave. Defer-max THR=8; packed-f16 alpha; f32 softmax.
__global__ __launch_bounds__(128) void k_agg4(
                      const _Float16* __restrict__ xl, const _Float16* __restrict__ xr,
                      const float* __restrict__ We, const float* __restrict__ att, const float* __restrict__ bo,
                      const float* __restrict__ gam, const float* __restrict__ bet,
                      const int* __restrict__ rowptr, const int* __restrict__ csr_src,
                      const float* __restrict__ csr_w,
                      u16* __restrict__ oh, u16* __restrict__ ol, int n){
  constexpr int HC_ = 512;
  constexpr float RT = 8.f;
  constexpr int NB = 2;
  int t = threadIdx.x;
  int widx = t >> 6, lane = t & 63;
  int l16 = lane & 15, grp = lane >> 4;    // grp = head
  int c0 = grp*128 + l16*8;                // 8 channels per lane, unique per lane

  // edge-phase params in f16 only (keeps loop VGPRs low)
  float4 wea = *(const float4*)&We[c0],  web = *(const float4*)&We[c0 + 4];
  float4 ata = *(const float4*)&att[c0], atb = *(const float4*)&att[c0 + 4];
  f16x8 weh, ath;
  #pragma unroll
  for (int j = 0; j < 4; j++){
    weh[j] = (_Float16)((&wea.x)[j]); weh[4+j] = (_Float16)((&web.x)[j]);
    ath[j] = (_Float16)((&ata.x)[j]); ath[4+j] = (_Float16)((&atb.x)[j]);
  }

  #pragma unroll 1
  for (int ib = 0; ib < NB; ib++){
    int nid = blockIdx.x*(2*NB) + widx*NB + ib;
    if (nid >= n) continue;                // wave-uniform; no barriers anywhere

    f16x8 xrh = *(const f16x8*)(xr + (size_t)nid*HC_ + c0);
    int rs = __builtin_amdgcn_readfirstlane(rowptr[nid]);
    int re = __builtin_amdgcn_readfirstlane(rowptr[nid + 1]);

    float m = -3e38f, d = 0.f;
    float acc[8] = {};
    for (int e0 = rs; e0 < re; e0 += 2){
      int e1 = e0 + 1;
      bool has1 = e1 < re;
      int s0 = csr_src[e0];
      int s1 = has1 ? csr_src[e1] : s0;
      float w0 = csr_w[e0];
      float w1 = has1 ? csr_w[e1] : 0.f;
      f16x8 hv0 = *(const f16x8*)(xl + (size_t)s0*HC_ + c0);
      f16x8 hv1 = *(const f16x8*)(xl + (size_t)s1*HC_ + c0);
      float p0 = alpha8(hv0, xrh, (_Float16)w0, weh, ath);
      float p1 = alpha8(hv1, xrh, (_Float16)w1, weh, ath);
      #pragma unroll
      for (int o = 1; o < 16; o <<= 1){    // reduce within 16-lane head group
        p0 += __shfl_xor(p0, o, 64);
        p1 += __shfl_xor(p1, o, 64);
      }
      if (!has1) p1 = -3e38f;
      float pm = fmaxf(p0, p1);
      if (pm > m + RT){                    // rare rescale (defer-max)
        float sc = __expf(m - pm);
        d *= sc;
        #pragma unroll
        for (int j = 0; j < 8; j++) acc[j] *= sc;
        m = pm;
      }
      float e0x = __expf(p0 - m), e1x = __expf(p1 - m);
      d += e0x + e1x;
      float v0[8], v1[8];
      #pragma unroll
      for (int j = 0; j < 8; j++){ v0[j] = (float)hv0[j]; v1[j] = (float)hv1[j]; }
      #pragma unroll
      for (int j = 0; j < 8; j++) acc[j] += e0x*v0[j] + e1x*v1[j];
    }
    // each head group processed ALL edges -> no cross-group merge needed
    float inv = 1.f / (d + 1e-16f);
    float4 boa = *(const float4*)&bo[c0], bob = *(const float4*)&bo[c0 + 4];
    float o8[8];
    #pragma unroll
    for (int j = 0; j < 4; j++){
      o8[j]   = acc[j]*inv   + (&boa.x)[j];
      o8[4+j] = acc[4+j]*inv + (&bob.x)[j];
    }

    // LayerNorm over all 512 channels: in-wave 6-step butterfly
    float s1 = 0.f, s2 = 0.f;
    #pragma unroll
    for (int j = 0; j < 8; j++){ s1 += o8[j]; s2 += o8[j]*o8[j]; }
    #pragma unroll
    for (int o = 1; o < 64; o <<= 1){ s1 += __shfl_xor(s1, o, 64); s2 += __shfl_xor(s2, o, 64); }
    float mu = s1 / (float)HC_;
    float var = s2 / (float)HC_ - mu*mu;
    float rstd = rsqrtf(var + 1e-5f);
    float4 ga = *(const float4*)&gam[c0], gb = *(const float4*)&gam[c0 + 4];
    float4 ba = *(const float4*)&bet[c0], bb = *(const float4*)&bet[c0 + 4];
    float y[8];
    #pragma unroll
    for (int j = 0; j < 4; j++){
      float ya = (o8[j]   - mu)*rstd*(&ga.x)[j] + (&ba.x)[j];
      float yb = (o8[4+j] - mu)*rstd*(&gb.x)[j] + (&bb.x)[j];
      y[j]   = (ya > 0.f) ? ya : (__expf(ya) - 1.f);   // ELU
      y[4+j] = (yb > 0.f) ? yb : (__expf(yb) - 1.f);
    }
    // every lane writes its own 8 channels: hi/lo bf16 planes, 16B each
    u32 hv2[4], lv2[4];
    #pragma unroll
    for (int j = 0; j < 4; j++){
      u16 h0 = f2bf(y[2*j]), h1 = f2bf(y[2*j+1]);
      u16 l0 = f2bf(y[2*j] - bf2f(h0)), l1 = f2bf(y[2*j+1] - bf2f(h1));
      hv2[j] = (u32)h0 | ((u32)h1 << 16);
      lv2[j] = (u32)l0 | ((u32)l1 << 16);
    }
    *(uint4*)&oh[(size_t)nid*HC_ + c0] = make_uint4(hv2[0],hv2[1],hv2[2],hv2[3]);
    *(uint4*)&ol[(size_t)nid*HC_ + c0] = make_uint4(lv2[0],lv2[1],lv2[2],lv2[3]);
  }
}

// ---------------- layer-3 agg (1 head, no ELU, f32 out): one node per 16-lane group ----------------
// 64-thread blocks; wave = 4 groups = 4 nodes. No cross-group merge; LN group-local.
__global__ __launch_bounds__(64) void k_agg1(
                      const _Float16* __restrict__ xl, const _Float16* __restrict__ xr,
                      const float* __restrict__ We, const float* __restrict__ att, const float* __restrict__ bo,
                      const float* __restrict__ gam, const float* __restrict__ bet,
                      const int* __restrict__ rowptr, const int* __restrict__ csr_src,
                      const float* __restrict__ csr_w,
                      float* __restrict__ out, int n){
  constexpr float RT = 8.f;
  int lane = threadIdx.x;
  int l16 = lane & 15, grp = lane >> 4;
  int c0 = l16*8;

  float4 wea = *(const float4*)&We[c0],  web = *(const float4*)&We[c0 + 4];
  float4 ata = *(const float4*)&att[c0], atb = *(const float4*)&att[c0 + 4];
  float4 boa = *(const float4*)&bo[c0],  bob = *(const float4*)&bo[c0 + 4];
  float4 ga  = *(const float4*)&gam[c0], gb  = *(const float4*)&gam[c0 + 4];
  float4 ba  = *(const float4*)&bet[c0], bb  = *(const float4*)&bet[c0 + 4];
  float bo8[8] = {boa.x,boa.y,boa.z,boa.w,bob.x,bob.y,bob.z,bob.w};
  float g8[8]  = {ga.x,ga.y,ga.z,ga.w,gb.x,gb.y,gb.z,gb.w};
  float b8[8]  = {ba.x,ba.y,ba.z,ba.w,bb.x,bb.y,bb.z,bb.w};
  f16x8 weh, ath;
  #pragma unroll
  for (int j = 0; j < 4; j++){
    weh[j] = (_Float16)((&wea.x)[j]); weh[4+j] = (_Float16)((&web.x)[j]);
    ath[j] = (_Float16)((&ata.x)[j]); ath[4+j] = (_Float16)((&atb.x)[j]);
  }

  int nid = blockIdx.x*4 + grp;
  if (nid >= n) return;            // per-group; no barriers below

  f16x8 xrh = *(const f16x8*)(xr + (size_t)nid*128 + c0);
  int rs = rowptr[nid], re = rowptr[nid + 1];
  float m = -3e38f, d = 0.f;
  float acc[8] = {};
  for (int e0 = rs; e0 < re; e0 += 2){
    int e1 = e0 + 1;
    bool has1 = e1 < re;
    int s0 = csr_src[e0];
    int s1 = has1 ? csr_src[e1] : s0;
    float w0 = csr_w[e0];
    float w1 = has1 ? csr_w[e1] : 0.f;
    f16x8 hv0 = *(const f16x8*)(xl + (size_t)s0*128 + c0);
    f16x8 hv1 = *(const f16x8*)(xl + (size_t)s1*128 + c0);
    float p0 = alpha8(hv0, xrh, (_Float16)w0, weh, ath);
    float p1 = alpha8(hv1, xrh, (_Float16)w1, weh, ath);
    #pragma unroll
    for (int o = 1; o < 16; o <<= 1){
      p0 += __shfl_xor(p0, o, 64);
      p1 += __shfl_xor(p1, o, 64);
    }
    if (!has1) p1 = -3e38f;
    float pm = fmaxf(p0, p1);
    if (pm > m + RT){
      float sc = __expf(m - pm);
      d *= sc;
      #pragma unroll
      for (int j = 0; j < 8; j++) acc[j] *= sc;
      m = pm;
    }
    float e0x = __expf(p0 - m), e1x = __expf(p1 - m);
    d += e0x + e1x;
    float v0[8], v1[8];
    #pragma unroll
    for (int j = 0; j < 8; j++){ v0[j] = (float)hv0[j]; v1[j] = (float)hv1[j]; }
    #pragma unroll
    for (int j = 0; j < 8; j++) acc[j] += e0x*v0[j] + e1x*v1[j];
  }
  float inv = 1.f / (d + 1e-16f);
  float o8[8];
  #pragma unroll
  for (int j = 0; j < 8; j++) o8[j] = acc[j]*inv + bo8[j];

  // LayerNorm over 128 channels (group-local)
  float s1 = 0.f, s2 = 0.f;
  #pragma unroll
  for (int j = 0; j < 8; j++){ s1 += o8[j]; s2 += o8[j]*o8[j]; }
  #pragma unroll
  for (int o = 1; o < 16; o <<= 1){ s1 += __shfl_xor(s1, o, 64); s2 += __shfl_xor(s2, o, 64); }
  float mu = s1 / 128.f;
  float var = s2 / 128.f - mu*mu;
  float rstd = rsqrtf(var + 1e-5f);
  float y[8];
  #pragma unroll
  for (int j = 0; j < 8; j++) y[j] = (o8[j] - mu)*rstd*g8[j] + b8[j];
  float* orow = out + (size_t)nid*128 + c0;
  *(float4*)orow       = make_float4(y[0],y[1],y[2],y[3]);
  *(float4*)(orow + 4) = make_float4(y[4],y[5],y[6],y[7]);
}

// ---------------- policy/value heads on one node ----------------
__global__ __launch_bounds__(128) void k_heads(const float* __restrict__ h3, const int* __restrict__ idxp,
        const float* __restrict__ Pw1, const float* __restrict__ Pb1,
        const float* __restrict__ Pw2, const float* __restrict__ Pb2,
        const float* __restrict__ Vw1, const float* __restrict__ Vb1,
        const float* __restrict__ Vw2, const float* __restrict__ Vb2,
        float* __restrict__ out){
  __shared__ float z[128], hp[128], hv[128];
  int t = threadIdx.x;
  int idx = *idxp;
  z[t] = h3[(size_t)idx*128 + t];
  __syncthreads();
  float sp = Pb1[t], sv = Vb1[t];
  for (int c = 0; c < 128; c++){
    float zc = z[c];
    sp += Pw1[t*128 + c] * zc;
    sv += Vw1[t*128 + c] * zc;
  }
  hp[t] = fmaxf(sp, 0.f);
  hv[t] = fmaxf(sv, 0.f);
  __syncthreads();
  if (t < 64){
    float l0 = Pw2[t]*hp[t]       + Pw2[64 + t]*hp[64 + t];
    float l1 = Pw2[128 + t]*hp[t] + Pw2[192 + t]*hp[64 + t];
    float vv = Vw2[t]*hv[t]       + Vw2[64 + t]*hv[64 + t];
    #pragma unroll
    for (int o = 1; o < 64; o <<= 1){
      l0 += __shfl_xor(l0, o, 64); l1 += __shfl_xor(l1, o, 64); vv += __shfl_xor(vv, o, 64);
    }
    if (t == 0){ out[0] = l0 + Pb2[0]; out[1] = l1 + Pb2[1]; out[2] = vv + Vb2[0]; }
  }
}

extern "C" void kernel_launch(void* const* d_in, const int* in_sizes, int n_in,
                              void* d_out, int out_size, void* d_ws, size_t ws_size,
                              hipStream_t stream){
  const float* x    = (const float*)d_in[0];
  const int*   ei   = (const int*)d_in[1];
  const float* ew   = (const float*)d_in[2];
  const int*   nidx = (const int*)d_in[3];
  const float* Wl1 = (const float*)d_in[4];  const float* bl1 = (const float*)d_in[5];
  const float* Wr1 = (const float*)d_in[6];  const float* br1 = (const float*)d_in[7];
  const float* We1 = (const float*)d_in[8];  const float* att1 = (const float*)d_in[9];
  const float* bo1 = (const float*)d_in[10];
  const float* Wl2 = (const float*)d_in[11]; const float* bl2 = (const float*)d_in[12];
  const float* Wr2 = (const float*)d_in[13]; const float* br2 = (const float*)d_in[14];
  const float* We2 = (const float*)d_in[15]; const float* att2 = (const float*)d_in[16];
  const float* bo2 = (const float*)d_in[17];
  const float* Wl3 = (const float*)d_in[18]; const float* bl3 = (const float*)d_in[19];
  const float* Wr3 = (const float*)d_in[20]; const float* br3 = (const float*)d_in[21];
  const float* We3 = (const float*)d_in[22]; const float* att3 = (const float*)d_in[23];
  const float* bo3 = (const float*)d_in[24];
  const float* gn1 = (const float*)d_in[25]; const float* bn1 = (const float*)d_in[26];
  const float* gn2 = (const float*)d_in[27]; const float* bn2 = (const float*)d_in[28];
  const float* gn3 = (const float*)d_in[29]; const float* bn3 = (const float*)d_in[30];
  const float* Pw1 = (const float*)d_in[31]; const float* Pb1 = (const float*)d_in[32];
  const float* Pw2 = (const float*)d_in[33]; const float* Pb2 = (const float*)d_in[34];
  const float* Vw1 = (const float*)d_in[35]; const float* Vb1 = (const float*)d_in[36];
  const float* Vw2 = (const float*)d_in[37]; const float* Vb2 = (const float*)d_in[38];

  const int N = in_sizes[0] / 16;
  const int E = in_sizes[2];
  const int NE = N + E;

  char* w = (char*)d_ws;
  size_t off = 0;
  float* sum_ew = (float*)(w + off); off += 256;
  int* rowptr = (int*)(w + off); off += (size_t)(N + 1)*4; off = (off + 255) & ~(size_t)255;
  int* cursor = (int*)(w + off); off += (size_t)N*4;       off = (off + 255) & ~(size_t)255;
  int* deg    = (int*)(w + off); off += (size_t)N*4;       off = (off + 255) & ~(size_t)255;
  int* csr_src= (int*)(w + off); off += (size_t)NE*4;      off = (off + 255) & ~(size_t)255;
  float* csr_w= (float*)(w + off); off += (size_t)NE*4;    off = (off + 255) & ~(size_t)255;
  // weight bf16 planes (single hi plane each)
  u16* W2lh = (u16*)(w + off); off += (size_t)512*512*2;
  u16* W2rh = (u16*)(w + off); off += (size_t)512*512*2;
  u16* W3lh = (u16*)(w + off); off += (size_t)128*512*2;
  u16* W3rh = (u16*)(w + off); off += (size_t)128*512*2;
  off = (off + 1048575) & ~(size_t)1048575;   // 1MB align for big buffers
  _Float16* A  = (_Float16*)(w + off); off += (size_t)N*512*2;
  _Float16* B  = (_Float16*)(w + off); off += (size_t)N*512*2;
  u16*   Ch = (u16*)(w + off);   off += (size_t)N*512*2;
  u16*   Cl = (u16*)(w + off);   off += (size_t)N*512*2;
  float* D  = (float*)(w + off); off += (size_t)N*128*4;
  (void)ws_size; (void)n_in; (void)out_size;

  hipMemsetAsync(sum_ew, 0, 4, stream);
  hipMemsetAsync(deg, 0, (size_t)N*4, stream);

  k_prep<<<256, 256, 0, stream>>>(ei + E, ew, E, deg, sum_ew);
  k_scan<<<1, 1024, 0, stream>>>(deg, rowptr, cursor, N);
  k_scatter<<<(NE + 255)/256, 256, 0, stream>>>(ei, ew, E, N, sum_ew, cursor, csr_src, csr_w);
  k_splitW<<<2560, 256, 0, stream>>>(Wl2, Wr2, Wl3, Wr3, W2lh, W2rh, W3lh, W3rh);

  const int GY = (N + 127)/128;

  // Layer 1
  k_lin1<<<N/32, 256, 0, stream>>>(x, Wl1, bl1, Wr1, br1, A, B, N);
  k_agg4<<<(N + 3)/4, 128, 0, stream>>>(A, B, We1, att1, bo1, gn1, bn1,
                                        rowptr, csr_src, csr_w, Ch, Cl, N);
  // Layer 2 (fused Wl+Wr dispatch)
  k_gemm_mfma<<<dim3(8, GY), 256, 0, stream>>>(Ch, Cl, W2lh, W2rh, bl2, br2, A, B, N, 512, 512);
  k_agg4<<<(N + 3)/4, 128, 0, stream>>>(A, B, We2, att2, bo2, gn2, bn2,
                                        rowptr, csr_src, csr_w, Ch, Cl, N);
  // Layer 3 (fused)
  k_gemm_mfma<<<dim3(2, GY), 256, 0, stream>>>(Ch, Cl, W3lh, W3rh, bl3, br3, A, B, N, 512, 128);
  k_agg1<<<(N + 3)/4, 64, 0, stream>>>(A, B, We3, att3, bo3, gn3, bn3,
                                       rowptr, csr_src, csr_w, D, N);
  // Heads
  k_heads<<<1, 128, 0, stream>>>(D, nidx, Pw1, Pb1, Pw2, Pb2, Vw1, Vb1, Vw2, Vb2, (float*)d_out);
}